// Round 8
// baseline (330.638 us; speedup 1.0000x reference)
//
#include <hip/hip_runtime.h>
#include <hip/hip_bf16.h>

#define NEG 0.01f
#define EPS 1e-5f

typedef __attribute__((ext_vector_type(8))) short short8;
typedef __attribute__((ext_vector_type(4))) float floatx4;

__device__ inline unsigned short f2bf(float f) {
    __hip_bfloat16 h = __float2bfloat16(f);
    union { __hip_bfloat16 h; unsigned short u; } cv; cv.h = h;
    return cv.u;
}

// ------------------------------- head: render + weight transform (fused) ----
// blocks [0,1024): render batch b=blk>>4, 256-px chunk blk&15
// blocks [1024,5144): weight transform, 1,054,720 threads total
__global__ __launch_bounds__(256) void head_kernel(const float* __restrict__ in,
                                                   unsigned short* __restrict__ out,
                                                   const float* __restrict__ w1,
                                                   const float* __restrict__ w2,
                                                   const float* __restrict__ w3,
                                                   unsigned short* __restrict__ wT1,
                                                   unsigned short* __restrict__ wT2,
                                                   unsigned short* __restrict__ wT3) {
    __shared__ float r0[46], r1[46], r2[46], r3[46];
    __shared__ float cls_s[46 * 14];
    if (blockIdx.x >= 1024) {
        int idx = (blockIdx.x - 1024) * 256 + threadIdx.x;
        const float* w; unsigned short* wT; int CIN, CPLOG, SUB, COLOG;
        if (idx < 30720) { w = w1; wT = wT1; CIN = 14; CPLOG = 4; SUB = 3; COLOG = 6; }
        else if (idx < 235520) { idx -= 30720; w = w2; wT = wT2; CIN = 64; CPLOG = 6; SUB = 10; COLOG = 7; }
        else if (idx < 1054720) { idx -= 235520; w = w3; wT = wT3; CIN = 128; CPLOG = 7; SUB = 20; COLOG = 8; }
        else return;
        int kk = idx & 31;
        int co = (idx >> 5) & ((1 << COLOG) - 1);
        int s = idx >> (5 + COLOG);
        int kh = s / SUB, sub = s - kh * SUB;
        int kidx = sub * 32 + kk;
        int kw = kidx >> CPLOG;
        int ci = kidx & ((1 << CPLOG) - 1);
        float v = (kw < 5 && ci < CIN) ? w[((size_t)(co * CIN + ci) * 5 + kh) * 5 + kw] : 0.f;
        wT[idx] = f2bf(v);
        return;
    }
    int b = blockIdx.x >> 4;
    int chunk = blockIdx.x & 15;
    int tid = threadIdx.x;
    if (tid < 46) {
        const float* p = in + ((size_t)b * 46 + tid) * 18 + 14;
        float x = p[0] * 64.f, y = p[1] * 64.f, w = p[2] * 64.f, h = p[3] * 64.f;
        r0[tid] = x - 0.5f * w; r1[tid] = x + 0.5f * w;
        r2[tid] = y - 0.5f * h; r3[tid] = y + 0.5f * h;
    }
    for (int idx = tid; idx < 46 * 14; idx += 256) {
        int n = idx / 14, c = idx % 14;
        cls_s[idx] = in[((size_t)b * 46 + n) * 18 + c];
    }
    __syncthreads();
    if (tid < 33) {
        int j = chunk * 33 + tid;
        if (j < 528) {
            int y, x;
            if (j < 136) { y = j / 68; x = j - y * 68; }
            else if (j < 272) { int t = j - 136; int yy = t / 68; y = 66 + yy; x = t - yy * 68; }
            else { int t = j - 272; y = 2 + (t >> 2); int k = t & 3; x = (k < 2) ? k : 64 + k; }
            size_t zb = (((size_t)b * 68 + y) * 68 + x) * 16;
            short8 z;
#pragma unroll
            for (int i = 0; i < 8; ++i) z[i] = 0;
            *(short8*)(out + zb) = z;
            *(short8*)(out + zb + 8) = z;
        }
    }
    int pix = chunk * 256 + tid;
    float cx = (float)(pix & 63);
    float cy = (float)(pix >> 6);
    float acc[14];
#pragma unroll
    for (int c = 0; c < 14; ++c) acc[c] = 0.f;
    for (int n = 0; n < 46; ++n) {
        float x0 = r0[n], x1 = r1[n], y0 = r2[n], y1 = r3[n];
        float by = fminf(fmaxf(cy - y0, 0.f), 1.f) * fminf(fmaxf(y1 - cy, 0.f), 1.f);
        float bx = fminf(fmaxf(cx - x0, 0.f), 1.f) * fminf(fmaxf(x1 - cx, 0.f), 1.f);
        float kx0 = fmaxf(1.f - fabsf(cx - x0), 0.f);
        float kx1 = fmaxf(1.f - fabsf(cx - x1), 0.f);
        float ky0 = fmaxf(1.f - fabsf(cy - y0), 0.f);
        float ky1 = fmaxf(1.f - fabsf(cy - y1), 0.f);
        float r = fmaxf(fmaxf(kx0 * by, kx1 * by), fmaxf(ky0 * bx, ky1 * bx));
        if (r > 0.f) {
#pragma unroll
            for (int c = 0; c < 14; ++c) acc[c] = fmaf(cls_s[n * 14 + c], r, acc[c]);
        }
    }
    size_t obase = (((size_t)b * 68 + ((pix >> 6) + 2)) * 68 + ((pix & 63) + 2)) * 16;
    short8 v0, v1;
#pragma unroll
    for (int i = 0; i < 8; ++i) v0[i] = (short)f2bf(acc[i]);
#pragma unroll
    for (int i = 0; i < 6; ++i) v1[i] = (short)f2bf(acc[8 + i]);
    v1[6] = 0; v1[7] = 0;
    *(short8*)(out + obase) = v0;
    *(short8*)(out + obase + 8) = v1;
}

// ------------------------------------------- implicit-GEMM MFMA conv --------
// (unchanged verified R4/R6 kernel; used for conv1 only)
template <int CP, int COUT, int HP, int LOG_OHW, int LOG_OW, int SUB,
          int NCO, int NT, int CH, int NW, int KSEG>
__global__ __launch_bounds__(NW * 64) void conv_mfma(
        const unsigned short* __restrict__ inP,
        const unsigned short* __restrict__ wT,
        float* __restrict__ outX,
        float* __restrict__ stacc) {
    constexpr int NSTEP_TOT = 5 * SUB;
    constexpr int NSTEP = NSTEP_TOT / KSEG;
    constexpr int NCHUNK = NSTEP / CH;
    constexpr int COT = NT * 16;
    constexpr int NSV = CH * COT * 4;
    constexpr int NSTG = (NSV + NW * 64 - 1) / (NW * 64);
    static_assert(NSTEP_TOT % KSEG == 0, "KSEG must divide total steps");
    static_assert(NSTEP % CH == 0, "CH must divide NSTEP");
    __shared__ short Bs[2][CH][COT][32];
    __shared__ float sred[NW][2][COT];
    int tid = threadIdx.x;
    int wave = tid >> 6, lane = tid & 63, q = lane >> 4, l16 = lane & 15;
    int cpx = gridDim.x >> 3;
    int lb = (blockIdx.x & 7) * cpx + (blockIdx.x >> 3);
    int bm = lb / (NCO * KSEG);
    int rem = lb - bm * (NCO * KSEG);
    int bco = rem / KSEG;
    int kseg = rem - bco * KSEG;
    int kbase = kseg * NSTEP;

    const short* aB[4];
#pragma unroll
    for (int f = 0; f < 4; ++f) {
        int m = bm * (NW * 64) + wave * 64 + f * 16 + l16;
        int b = m >> LOG_OHW;
        int ohw = m & ((1 << LOG_OHW) - 1);
        int oh = ohw >> LOG_OW, ow = ohw & ((1 << LOG_OW) - 1);
        aB[f] = (const short*)inP + ((size_t)((b * HP + 2 * oh) * HP + 2 * ow)) * CP + q * 8;
    }
    const short* bgbase = (const short*)wT + (size_t)bco * COT * 32;

    floatx4 acc[4][NT];
#pragma unroll
    for (int f = 0; f < 4; ++f)
#pragma unroll
        for (int nt = 0; nt < NT; ++nt) acc[f][nt] = (floatx4){0.f, 0.f, 0.f, 0.f};

    short8 nb[NSTG];
#pragma unroll
    for (int i = 0; i < NSTG; ++i) {
        int v = tid + i * NW * 64;
        if (v < NSV) {
            int s = v / (COT * 4);
            int rem2 = v - s * (COT * 4);
            nb[i] = *(const short8*)(bgbase + ((size_t)(kbase + s) * COUT) * 32 + rem2 * 8);
        }
    }
#pragma unroll
    for (int i = 0; i < NSTG; ++i) {
        int v = tid + i * NW * 64;
        if (v < NSV) {
            int s = v / (COT * 4);
            int rem2 = v - s * (COT * 4);
            *(short8*)((short*)&Bs[0][s][0][0] + rem2 * 8) = nb[i];
        }
    }
    short8 afc[4], afn[4];
    {
        int kh0 = kbase / SUB, sub0 = kbase - kh0 * SUB;
#pragma unroll
        for (int f = 0; f < 4; ++f)
            afc[f] = *(const short8*)(aB[f] + (size_t)(kh0 * HP) * CP + sub0 * 32);
    }
    __syncthreads();

    for (int chunk = 0; chunk < NCHUNK; ++chunk) {
        int cur = chunk & 1;
        if (chunk + 1 < NCHUNK) {
            int step0 = kbase + (chunk + 1) * CH;
#pragma unroll
            for (int i = 0; i < NSTG; ++i) {
                int v = tid + i * NW * 64;
                if (v < NSV) {
                    int s = v / (COT * 4);
                    int rem2 = v - s * (COT * 4);
                    nb[i] = *(const short8*)(bgbase + ((size_t)(step0 + s) * COUT) * 32 + rem2 * 8);
                }
            }
        }
#pragma unroll
        for (int s = 0; s < CH; ++s) {
            int lstep = chunk * CH + s;
            if (lstep + 1 < NSTEP) {
                int gsn = kbase + lstep + 1;
                int khn = gsn / SUB, subn = gsn - khn * SUB;
#pragma unroll
                for (int f = 0; f < 4; ++f)
                    afn[f] = *(const short8*)(aB[f] + (size_t)(khn * HP) * CP + subn * 32);
            }
#pragma unroll
            for (int nt = 0; nt < NT; ++nt) {
                short8 bf = *(const short8*)&Bs[cur][s][nt * 16 + l16][q * 8];
#pragma unroll
                for (int f = 0; f < 4; ++f)
                    acc[f][nt] = __builtin_amdgcn_mfma_f32_16x16x32_bf16(afc[f], bf, acc[f][nt], 0, 0, 0);
            }
#pragma unroll
            for (int f = 0; f < 4; ++f) afc[f] = afn[f];
        }
        if (chunk + 1 < NCHUNK) {
#pragma unroll
            for (int i = 0; i < NSTG; ++i) {
                int v = tid + i * NW * 64;
                if (v < NSV) {
                    int s = v / (COT * 4);
                    int rem2 = v - s * (COT * 4);
                    *(short8*)((short*)&Bs[cur ^ 1][s][0][0] + rem2 * 8) = nb[i];
                }
            }
            __syncthreads();
        }
    }
#pragma unroll
    for (int f = 0; f < 4; ++f)
#pragma unroll
        for (int nt = 0; nt < NT; ++nt)
#pragma unroll
            for (int rg = 0; rg < 4; ++rg) {
                int mg = bm * (NW * 64) + wave * 64 + f * 16 + q * 4 + rg;
                int co = bco * COT + nt * 16 + l16;
                if constexpr (KSEG > 1)
                    atomicAdd(&outX[(size_t)mg * COUT + co], acc[f][nt][rg]);
                else
                    outX[(size_t)mg * COUT + co] = acc[f][nt][rg];
            }
    if constexpr (KSEG == 1) {
#pragma unroll
        for (int nt = 0; nt < NT; ++nt) {
            float s = 0.f, s2 = 0.f;
#pragma unroll
            for (int f = 0; f < 4; ++f)
#pragma unroll
                for (int rg = 0; rg < 4; ++rg) {
                    float v = acc[f][nt][rg];
                    s += v; s2 = fmaf(v, v, s2);
                }
            s += __shfl_xor(s, 16); s += __shfl_xor(s, 32);
            s2 += __shfl_xor(s2, 16); s2 += __shfl_xor(s2, 32);
            if (q == 0) {
                sred[wave][0][nt * 16 + l16] = s;
                sred[wave][1][nt * 16 + l16] = s2;
            }
        }
        __syncthreads();
        if (tid < COT) {
            float ts = 0.f, ts2 = 0.f;
#pragma unroll
            for (int w = 0; w < NW; ++w) { ts += sred[w][0][tid]; ts2 += sred[w][1][tid]; }
            atomicAdd(&stacc[bco * COT + tid], ts);
            atomicAdd(&stacc[COUT + bco * COT + tid], ts2);
        }
    }
}

// --------------- conv2 with BN1+lrelu+pad fused into the A-loader -----------
// Reads conv1out f32 [65536][64] + st1(sum,sumsq); applies per-channel affine
// + lrelu + bf16 round at load time (bit-identical to the old pad1 path).
// Out-of-bounds spatial -> 0 (pad). Geometry = R4 conv2: NCO=4, NT=2, CH=10
// (=SUB so sub==s compile-time -> BN coeff octet select folds to registers).
__global__ __launch_bounds__(256) void conv2_fused(
        const float* __restrict__ prev,
        const float* __restrict__ st,
        const float* __restrict__ gg,
        const float* __restrict__ bbp,
        const unsigned short* __restrict__ wT,
        float* __restrict__ outX,
        float* __restrict__ stacc) {
    constexpr int COUT = 128, NCO = 4, NT = 2, CH = 10, NW = 4;
    constexpr int NCHUNK = 5, COT = 32, NSV = CH * COT * 4, NSTG = NSV / (NW * 64);
    __shared__ short Bs[2][CH][COT][32];
    __shared__ float sred[NW][2][COT];
    int tid = threadIdx.x;
    int wave = tid >> 6, lane = tid & 63, q = lane >> 4, l16 = lane & 15;
    int cpx = gridDim.x >> 3;
    int lb = (blockIdx.x & 7) * cpx + (blockIdx.x >> 3);
    int bm = lb / NCO, bco = lb % NCO;

    int pB[4], oy[4], ox[4];
#pragma unroll
    for (int f = 0; f < 4; ++f) {
        int m = bm * (NW * 64) + wave * 64 + f * 16 + l16;
        int b = m >> 8, oh = (m >> 4) & 15, ow = m & 15;
        pB[f] = b * 1024; oy[f] = 2 * oh; ox[f] = 2 * ow;
    }
    // BN coefficients for this lane's two channel octets (ci = o*32 + q*8 + j)
    float sc_0[8], sh_0[8], sc_1[8], sh_1[8];
#pragma unroll
    for (int j = 0; j < 8; ++j) {
        int c0 = q * 8 + j, c1 = 32 + q * 8 + j;
        float m0 = st[c0] * (1.f / 65536.f), m1 = st[c1] * (1.f / 65536.f);
        float v0 = fmaxf(st[64 + c0] * (1.f / 65536.f) - m0 * m0, 0.f);
        float v1 = fmaxf(st[64 + c1] * (1.f / 65536.f) - m1 * m1, 0.f);
        sc_0[j] = gg[c0] * rsqrtf(v0 + EPS); sh_0[j] = bbp[c0] - m0 * sc_0[j];
        sc_1[j] = gg[c1] * rsqrtf(v1 + EPS); sh_1[j] = bbp[c1] - m1 * sc_1[j];
    }
    const short* bgbase = (const short*)wT + (size_t)bco * COT * 32;

    floatx4 acc[4][NT];
#pragma unroll
    for (int f = 0; f < 4; ++f)
#pragma unroll
        for (int nt = 0; nt < NT; ++nt) acc[f][nt] = (floatx4){0.f, 0.f, 0.f, 0.f};

    short8 nb[NSTG];
#pragma unroll
    for (int i = 0; i < NSTG; ++i) {
        int v = tid + i * NW * 64;
        int s = v / (COT * 4);
        int rem2 = v - s * (COT * 4);
        nb[i] = *(const short8*)(bgbase + ((size_t)s * COUT) * 32 + rem2 * 8);
    }
#pragma unroll
    for (int i = 0; i < NSTG; ++i) {
        int v = tid + i * NW * 64;
        int s = v / (COT * 4);
        int rem2 = v - s * (COT * 4);
        *(short8*)((short*)&Bs[0][s][0][0] + rem2 * 8) = nb[i];
    }
    __syncthreads();

    for (int chunk = 0; chunk < NCHUNK; ++chunk) {
        int cur = chunk & 1;
        if (chunk + 1 < NCHUNK) {
            int step0 = (chunk + 1) * CH;
#pragma unroll
            for (int i = 0; i < NSTG; ++i) {
                int v = tid + i * NW * 64;
                int s = v / (COT * 4);
                int rem2 = v - s * (COT * 4);
                nb[i] = *(const short8*)(bgbase + ((size_t)(step0 + s) * COUT) * 32 + rem2 * 8);
            }
        }
#pragma unroll
        for (int s = 0; s < CH; ++s) {
            // kh = chunk (CH==SUB), kw = s>>1, octet o = s&1
            int kw = s >> 1;
            short8 af[4];
#pragma unroll
            for (int f = 0; f < 4; ++f) {
                int y = oy[f] + chunk - 2, x = ox[f] + kw - 2;
                bool val = ((unsigned)y < 32u) && ((unsigned)x < 32u);
                float4 lo = {0.f, 0.f, 0.f, 0.f}, hi = {0.f, 0.f, 0.f, 0.f};
                if (val) {
                    const float* p = prev + ((size_t)(pB[f] + y * 32 + x)) * 64 + ((s & 1) * 32 + q * 8);
                    lo = *(const float4*)p; hi = *(const float4*)(p + 4);
                }
                float lv[4] = {lo.x, lo.y, lo.z, lo.w};
                float hv[4] = {hi.x, hi.y, hi.z, hi.w};
#pragma unroll
                for (int j = 0; j < 4; ++j) {
                    float t = fmaf(lv[j], (s & 1) ? sc_1[j] : sc_0[j], (s & 1) ? sh_1[j] : sh_0[j]);
                    t = fmaxf(t, t * NEG);
                    af[f][j] = val ? (short)f2bf(t) : (short)0;
                    float t2 = fmaf(hv[j], (s & 1) ? sc_1[4 + j] : sc_0[4 + j], (s & 1) ? sh_1[4 + j] : sh_0[4 + j]);
                    t2 = fmaxf(t2, t2 * NEG);
                    af[f][4 + j] = val ? (short)f2bf(t2) : (short)0;
                }
            }
#pragma unroll
            for (int nt = 0; nt < NT; ++nt) {
                short8 bf = *(const short8*)&Bs[cur][s][nt * 16 + l16][q * 8];
#pragma unroll
                for (int f = 0; f < 4; ++f)
                    acc[f][nt] = __builtin_amdgcn_mfma_f32_16x16x32_bf16(af[f], bf, acc[f][nt], 0, 0, 0);
            }
        }
        if (chunk + 1 < NCHUNK) {
#pragma unroll
            for (int i = 0; i < NSTG; ++i) {
                int v = tid + i * NW * 64;
                int s = v / (COT * 4);
                int rem2 = v - s * (COT * 4);
                *(short8*)((short*)&Bs[cur ^ 1][s][0][0] + rem2 * 8) = nb[i];
            }
            __syncthreads();
        }
    }
#pragma unroll
    for (int f = 0; f < 4; ++f)
#pragma unroll
        for (int nt = 0; nt < NT; ++nt)
#pragma unroll
            for (int rg = 0; rg < 4; ++rg) {
                int mg = bm * (NW * 64) + wave * 64 + f * 16 + q * 4 + rg;
                int co = bco * COT + nt * 16 + l16;
                outX[(size_t)mg * COUT + co] = acc[f][nt][rg];
            }
#pragma unroll
    for (int nt = 0; nt < NT; ++nt) {
        float s = 0.f, s2 = 0.f;
#pragma unroll
        for (int f = 0; f < 4; ++f)
#pragma unroll
            for (int rg = 0; rg < 4; ++rg) {
                float v = acc[f][nt][rg];
                s += v; s2 = fmaf(v, v, s2);
            }
        s += __shfl_xor(s, 16); s += __shfl_xor(s, 32);
        s2 += __shfl_xor(s2, 16); s2 += __shfl_xor(s2, 32);
        if (q == 0) {
            sred[wave][0][nt * 16 + l16] = s;
            sred[wave][1][nt * 16 + l16] = s2;
        }
    }
    __syncthreads();
    if (tid < COT) {
        float ts = 0.f, ts2 = 0.f;
#pragma unroll
        for (int w = 0; w < NW; ++w) { ts += sred[w][0][tid]; ts2 += sred[w][1][tid]; }
        atomicAdd(&stacc[bco * COT + tid], ts);
        atomicAdd(&stacc[COUT + bco * COT + tid], ts2);
    }
}

// --------------- conv3 with BN2+lrelu+pad fused into the A-loader -----------
// SUB=20, CH=10: sub = s (even chunk) or s+10 (odd chunk) -> two unrolled
// bodies behind a wave-uniform branch so the BN octet select stays
// compile-time (rule: no runtime-indexed register arrays).
#define C3SEL(SUBV, J, A0, A1, A2, A3) \
    ((((SUBV) & 3) == 0) ? (A0)[J] : (((SUBV) & 3) == 1) ? (A1)[J] : (((SUBV) & 3) == 2) ? (A2)[J] : (A3)[J])

#define C3_BODY(SIDX, KHV, SUBV)                                                         \
    {                                                                                    \
        const int kw_ = (SUBV) >> 2;                                                     \
        short8 af_[4];                                                                   \
        _Pragma("unroll")                                                                \
        for (int f = 0; f < 4; ++f) {                                                    \
            int y_ = oy[f] + (KHV) - 2, x_ = ox[f] + kw_ - 2;                            \
            bool val_ = ((unsigned)y_ < 16u) && ((unsigned)x_ < 16u);                    \
            float4 lo_ = {0.f, 0.f, 0.f, 0.f}, hi_ = {0.f, 0.f, 0.f, 0.f};               \
            if (val_) {                                                                  \
                const float* p_ = prev + ((size_t)(pB[f] + y_ * 16 + x_)) * 128          \
                                  + (((SUBV) & 3) * 32 + q * 8);                         \
                lo_ = *(const float4*)p_; hi_ = *(const float4*)(p_ + 4);                \
            }                                                                            \
            float lv_[4] = {lo_.x, lo_.y, lo_.z, lo_.w};                                 \
            float hv_[4] = {hi_.x, hi_.y, hi_.z, hi_.w};                                 \
            _Pragma("unroll")                                                            \
            for (int j = 0; j < 4; ++j) {                                                \
                float t = fmaf(lv_[j], C3SEL(SUBV, j, sc_0, sc_1, sc_2, sc_3),           \
                               C3SEL(SUBV, j, sh_0, sh_1, sh_2, sh_3));                  \
                t = fmaxf(t, t * NEG);                                                   \
                af_[f][j] = val_ ? (short)f2bf(t) : (short)0;                            \
                float t2 = fmaf(hv_[j], C3SEL(SUBV, j + 4, sc_0, sc_1, sc_2, sc_3),      \
                                C3SEL(SUBV, j + 4, sh_0, sh_1, sh_2, sh_3));             \
                t2 = fmaxf(t2, t2 * NEG);                                                \
                af_[f][4 + j] = val_ ? (short)f2bf(t2) : (short)0;                       \
            }                                                                            \
        }                                                                                \
        _Pragma("unroll")                                                                \
        for (int nt = 0; nt < 2; ++nt) {                                                 \
            short8 bf_ = *(const short8*)&Bs[cur][SIDX][nt * 16 + l16][q * 8];           \
            _Pragma("unroll")                                                            \
            for (int f = 0; f < 4; ++f)                                                  \
                acc[f][nt] = __builtin_amdgcn_mfma_f32_16x16x32_bf16(af_[f], bf_,        \
                                                                     acc[f][nt], 0, 0, 0); \
        }                                                                                \
    }

__global__ __launch_bounds__(128) void conv3_fused(
        const float* __restrict__ prev,
        const float* __restrict__ st,
        const float* __restrict__ gg,
        const float* __restrict__ bbp,
        const unsigned short* __restrict__ wT,
        float* __restrict__ outX,
        float* __restrict__ stacc) {
    constexpr int COUT = 256, NCO = 8, NT = 2, CH = 10, NW = 2;
    constexpr int NCHUNK = 10, COT = 32, NSV = CH * COT * 4, NSTG = NSV / (NW * 64);
    __shared__ short Bs[2][CH][COT][32];
    __shared__ float sred[NW][2][COT];
    int tid = threadIdx.x;
    int wave = tid >> 6, lane = tid & 63, q = lane >> 4, l16 = lane & 15;
    int cpx = gridDim.x >> 3;
    int lb = (blockIdx.x & 7) * cpx + (blockIdx.x >> 3);
    int bm = lb / NCO, bco = lb % NCO;

    int pB[4], oy[4], ox[4];
#pragma unroll
    for (int f = 0; f < 4; ++f) {
        int m = bm * (NW * 64) + wave * 64 + f * 16 + l16;
        int b = m >> 6, oh = (m >> 3) & 7, ow = m & 7;
        pB[f] = b * 256; oy[f] = 2 * oh; ox[f] = 2 * ow;
    }
    // BN coefficients for this lane's four channel octets (ci = o*32 + q*8 + j)
    float sc_0[8], sh_0[8], sc_1[8], sh_1[8], sc_2[8], sh_2[8], sc_3[8], sh_3[8];
#pragma unroll
    for (int j = 0; j < 8; ++j) {
        int cb = q * 8 + j;
#pragma unroll
        for (int o = 0; o < 4; ++o) {
            int c = o * 32 + cb;
            float mn = st[c] * (1.f / 16384.f);
            float vr = fmaxf(st[128 + c] * (1.f / 16384.f) - mn * mn, 0.f);
            float sc = gg[c] * rsqrtf(vr + EPS);
            float sh = bbp[c] - mn * sc;
            if (o == 0) { sc_0[j] = sc; sh_0[j] = sh; }
            else if (o == 1) { sc_1[j] = sc; sh_1[j] = sh; }
            else if (o == 2) { sc_2[j] = sc; sh_2[j] = sh; }
            else { sc_3[j] = sc; sh_3[j] = sh; }
        }
    }
    const short* bgbase = (const short*)wT + (size_t)bco * COT * 32;

    floatx4 acc[4][NT];
#pragma unroll
    for (int f = 0; f < 4; ++f)
#pragma unroll
        for (int nt = 0; nt < NT; ++nt) acc[f][nt] = (floatx4){0.f, 0.f, 0.f, 0.f};

    short8 nb[NSTG];
#pragma unroll
    for (int i = 0; i < NSTG; ++i) {
        int v = tid + i * NW * 64;
        int s = v / (COT * 4);
        int rem2 = v - s * (COT * 4);
        nb[i] = *(const short8*)(bgbase + ((size_t)s * COUT) * 32 + rem2 * 8);
    }
#pragma unroll
    for (int i = 0; i < NSTG; ++i) {
        int v = tid + i * NW * 64;
        int s = v / (COT * 4);
        int rem2 = v - s * (COT * 4);
        *(short8*)((short*)&Bs[0][s][0][0] + rem2 * 8) = nb[i];
    }
    __syncthreads();

    for (int chunk = 0; chunk < NCHUNK; ++chunk) {
        int cur = chunk & 1;
        if (chunk + 1 < NCHUNK) {
            int step0 = (chunk + 1) * CH;
#pragma unroll
            for (int i = 0; i < NSTG; ++i) {
                int v = tid + i * NW * 64;
                int s = v / (COT * 4);
                int rem2 = v - s * (COT * 4);
                nb[i] = *(const short8*)(bgbase + ((size_t)(step0 + s) * COUT) * 32 + rem2 * 8);
            }
        }
        int khh = chunk >> 1;
        if ((chunk & 1) == 0) {
#pragma unroll
            for (int s = 0; s < CH; ++s) C3_BODY(s, khh, s)
        } else {
#pragma unroll
            for (int s = 0; s < CH; ++s) C3_BODY(s, khh, (s + 10))
        }
        if (chunk + 1 < NCHUNK) {
#pragma unroll
            for (int i = 0; i < NSTG; ++i) {
                int v = tid + i * NW * 64;
                int s = v / (COT * 4);
                int rem2 = v - s * (COT * 4);
                *(short8*)((short*)&Bs[cur ^ 1][s][0][0] + rem2 * 8) = nb[i];
            }
            __syncthreads();
        }
    }
#pragma unroll
    for (int f = 0; f < 4; ++f)
#pragma unroll
        for (int nt = 0; nt < NT; ++nt)
#pragma unroll
            for (int rg = 0; rg < 4; ++rg) {
                int mg = bm * (NW * 64) + wave * 64 + f * 16 + q * 4 + rg;
                int co = bco * COT + nt * 16 + l16;
                outX[(size_t)mg * COUT + co] = acc[f][nt][rg];
            }
#pragma unroll
    for (int nt = 0; nt < NT; ++nt) {
        float s = 0.f, s2 = 0.f;
#pragma unroll
        for (int f = 0; f < 4; ++f)
#pragma unroll
            for (int rg = 0; rg < 4; ++rg) {
                float v = acc[f][nt][rg];
                s += v; s2 = fmaf(v, v, s2);
            }
        s += __shfl_xor(s, 16); s += __shfl_xor(s, 32);
        s2 += __shfl_xor(s2, 16); s2 += __shfl_xor(s2, 32);
        if (q == 0) {
            sred[wave][0][nt * 16 + l16] = s;
            sred[wave][1][nt * 16 + l16] = s2;
        }
    }
    __syncthreads();
    if (tid < COT) {
        float ts = 0.f, ts2 = 0.f;
#pragma unroll
        for (int w = 0; w < NW; ++w) { ts += sred[w][0][tid]; ts2 += sred[w][1][tid]; }
        atomicAdd(&stacc[bco * COT + tid], ts);
        atomicAdd(&stacc[COUT + bco * COT + tid], ts2);
    }
}

// --------------------------------------------------- conv4 split-K GEMM -----
__global__ __launch_bounds__(256) void conv4_mfma(const unsigned short* __restrict__ A,
                                                  const float* __restrict__ w4,
                                                  float* __restrict__ h4) {
    constexpr int CH = 4, NCHUNK = 8;
    __shared__ short Bs[CH][64][40];
    int tid = threadIdx.x;
    int bco = blockIdx.x & 15;
    int ks = blockIdx.x >> 4;
    int wave = tid >> 6, lane = tid & 63, q = lane >> 4, l16 = lane & 15;
    const short* aBase = (const short*)A + (size_t)(wave * 16 + l16) * 16384 + ks * 1024 + q * 8;
    int r = tid >> 2, cc = tid & 3;
    const float* bg = w4 + (size_t)(bco * 64 + r) * 16384 + ks * 1024 + cc * 8;

    floatx4 acc[4];
#pragma unroll
    for (int nt = 0; nt < 4; ++nt) acc[nt] = (floatx4){0.f, 0.f, 0.f, 0.f};

    short8 nb[CH];
#pragma unroll
    for (int s = 0; s < CH; ++s) {
        float4 b0 = *(const float4*)(bg + s * 32);
        float4 b1 = *(const float4*)(bg + s * 32 + 4);
        nb[s][0] = (short)f2bf(b0.x); nb[s][1] = (short)f2bf(b0.y);
        nb[s][2] = (short)f2bf(b0.z); nb[s][3] = (short)f2bf(b0.w);
        nb[s][4] = (short)f2bf(b1.x); nb[s][5] = (short)f2bf(b1.y);
        nb[s][6] = (short)f2bf(b1.z); nb[s][7] = (short)f2bf(b1.w);
    }
#pragma unroll
    for (int s = 0; s < CH; ++s) *(short8*)&Bs[s][r][cc * 8] = nb[s];
    __syncthreads();

    for (int chunk = 0; chunk < NCHUNK; ++chunk) {
        bool has_next = (chunk + 1 < NCHUNK);
        if (has_next) {
#pragma unroll
            for (int s = 0; s < CH; ++s) {
                int step = (chunk + 1) * CH + s;
                float4 b0 = *(const float4*)(bg + step * 32);
                float4 b1 = *(const float4*)(bg + step * 32 + 4);
                nb[s][0] = (short)f2bf(b0.x); nb[s][1] = (short)f2bf(b0.y);
                nb[s][2] = (short)f2bf(b0.z); nb[s][3] = (short)f2bf(b0.w);
                nb[s][4] = (short)f2bf(b1.x); nb[s][5] = (short)f2bf(b1.y);
                nb[s][6] = (short)f2bf(b1.z); nb[s][7] = (short)f2bf(b1.w);
            }
        }
#pragma unroll
        for (int s = 0; s < CH; ++s) {
            int step = chunk * CH + s;
            short8 af = *(const short8*)(aBase + step * 32);
#pragma unroll
            for (int nt = 0; nt < 4; ++nt) {
                short8 bf = *(const short8*)&Bs[s][nt * 16 + l16][q * 8];
                acc[nt] = __builtin_amdgcn_mfma_f32_16x16x32_bf16(af, bf, acc[nt], 0, 0, 0);
            }
        }
        if (has_next) {
            __syncthreads();
#pragma unroll
            for (int s = 0; s < CH; ++s) *(short8*)&Bs[s][r][cc * 8] = nb[s];
            __syncthreads();
        }
    }
#pragma unroll
    for (int nt = 0; nt < 4; ++nt) {
#pragma unroll
        for (int rg = 0; rg < 4; ++rg) {
            int mg = wave * 16 + q * 4 + rg;
            int co = bco * 64 + nt * 16 + l16;
            atomicAdd(&h4[(size_t)mg * 1024 + co], acc[nt][rg]);
        }
    }
}

// ----------------------------------------------------------- batch stats ----
__global__ __launch_bounds__(256) void stats_part(const float* __restrict__ X,
                                                  float* __restrict__ acc,
                                                  int CO, int R, int RPB, int CGLOG) {
    int tid = threadIdx.x;
    int cg = blockIdx.x & ((1 << CGLOG) - 1);
    int rb = blockIdx.x >> CGLOG;
    int c = (cg << 6) + (tid & 63);
    int w = tid >> 6;
    float s = 0.f, s2 = 0.f;
    int rend = min(R, (rb + 1) * RPB);
    for (int r = rb * RPB + w; r < rend; r += 4) {
        float v = X[(size_t)r * CO + c];
        s += v; s2 += v * v;
    }
    __shared__ float ls[4][64], ls2[4][64];
    ls[w][tid & 63] = s; ls2[w][tid & 63] = s2;
    __syncthreads();
    if (tid < 64) {
        float ts = ls[0][tid] + ls[1][tid] + ls[2][tid] + ls[3][tid];
        float ts2 = ls2[0][tid] + ls2[1][tid] + ls2[2][tid] + ls2[3][tid];
        int cc = (cg << 6) + tid;
        atomicAdd(&acc[cc], ts);
        atomicAdd(&acc[CO + cc], ts2);
    }
}

// -------- BN(inline finalize) + lrelu + bf16, NHWC -> NCHW (conv4 input) ----
__global__ __launch_bounds__(256) void bn_nchw_kernel(const float* __restrict__ X,
                                                      const float* __restrict__ stacc,
                                                      const float* __restrict__ g,
                                                      const float* __restrict__ bb,
                                                      unsigned short* __restrict__ out,
                                                      int total) {
    int idx = blockIdx.x * 256 + threadIdx.x;
    if (idx >= total) return;
    int hw = idx & 63;
    int ci = (idx >> 6) & 255;
    int b = idx >> 14;
    float mean = stacc[ci] * (1.f / 4096.f);
    float var = fmaxf(stacc[256 + ci] * (1.f / 4096.f) - mean * mean, 0.f);
    float sc = g[ci] * rsqrtf(var + EPS);
    float sh = bb[ci] - mean * sc;
    float f = X[((size_t)(b * 64 + hw)) * 256 + ci] * sc + sh;
    f = f >= 0.f ? f : NEG * f;
    out[idx] = f2bf(f);
}

// -------------------------------------- conv5 (inline BN4 finalize) ---------
__global__ __launch_bounds__(256) void conv5_kernel(const float* __restrict__ X,
                                                    const float* __restrict__ stacc,
                                                    const float* __restrict__ g,
                                                    const float* __restrict__ bb,
                                                    const float* __restrict__ w5,
                                                    const float* __restrict__ b5,
                                                    float* __restrict__ out) {
    int b = blockIdx.x, tid = threadIdx.x;
    float s = 0.f;
    for (int c = tid; c < 1024; c += 256) {
        float mean = stacc[c] * (1.f / 64.f);
        float var = fmaxf(stacc[1024 + c] * (1.f / 64.f) - mean * mean, 0.f);
        float sc = g[c] * rsqrtf(var + EPS);
        float sh = bb[c] - mean * sc;
        float f = X[(size_t)b * 1024 + c] * sc + sh;
        f = f >= 0.f ? f : NEG * f;
        s = fmaf(f, w5[c], s);
    }
#pragma unroll
    for (int off = 32; off > 0; off >>= 1) s += __shfl_down(s, off);
    __shared__ float ls[4];
    if ((tid & 63) == 0) ls[tid >> 6] = s;
    __syncthreads();
    if (tid == 0) out[b] = ls[0] + ls[1] + ls[2] + ls[3] + b5[0];
}

// ----------------------------------------------------------------- launch ---
extern "C" void kernel_launch(void* const* d_in, const int* in_sizes, int n_in,
                              void* d_out, int out_size, void* d_ws, size_t ws_size,
                              hipStream_t stream) {
    (void)in_sizes; (void)n_in; (void)out_size; (void)ws_size;
    const float* input_data = (const float*)d_in[0];
    const float* w1 = (const float*)d_in[2];
    const float* g1 = (const float*)d_in[3];
    const float* b1 = (const float*)d_in[4];
    const float* w2 = (const float*)d_in[5];
    const float* g2 = (const float*)d_in[6];
    const float* b2 = (const float*)d_in[7];
    const float* w3 = (const float*)d_in[8];
    const float* g3 = (const float*)d_in[9];
    const float* b3 = (const float*)d_in[10];
    const float* w4 = (const float*)d_in[11];
    const float* g4 = (const float*)d_in[12];
    const float* b4 = (const float*)d_in[13];
    const float* w5 = (const float*)d_in[14];
    const float* b5 = (const float*)d_in[15];

    char* ws = (char*)d_ws;
    float* regA = (float*)ws;               // 16.8 MB: conv1out, then conv3out
    char* wsB = ws + 16777216;              // 10.7 MB: conv2out (8.4 MB)
    char* wsC = wsB + 10616832;             // 9.5 MB: rendered, then a4
    char* wsD = wsC + 9469952;
    float* h4  = (float*)wsD;                               // 262,144 B
    float* st1 = (float*)(wsD + 262144);                    // 512 B  (64*2)
    float* st2 = (float*)(wsD + 262656);                    // 1024 B (128*2)
    float* st3 = (float*)(wsD + 263680);                    // 2048 B (256*2)
    float* st4 = (float*)(wsD + 265728);                    // 8192 B (1024*2)
    unsigned short* wT1 = (unsigned short*)(wsD + 274432);  // 61,440 B
    unsigned short* wT2 = (unsigned short*)(wsD + 335872);  // 409,600 B
    unsigned short* wT3 = (unsigned short*)(wsD + 745472);  // 1,638,400 B

    unsigned short* rendered = (unsigned short*)wsC;
    float* conv1out = regA;
    float* conv2out = (float*)wsB;
    float* conv3out = regA;                 // conv1out dead after conv2_fused
    unsigned short* a4 = (unsigned short*)wsC;  // rendered dead after conv1

    // one memset covers h4 + all stat accumulators
    hipMemsetAsync(wsD, 0, 273920, stream);
    // fused render + weight transform
    head_kernel<<<5144, 256, 0, stream>>>(input_data, rendered, w1, w2, w3, wT1, wT2, wT3);

    // conv1: [65536,480]x[480,64] — 256 blocks x 4 waves, NT=4, CH=5, fused stats
    conv_mfma<16, 64, 68, 10, 5, 3, 1, 4, 5, 4, 1><<<256, 256, 0, stream>>>(rendered, wT1, conv1out, st1);

    // conv2 (BN1+lrelu+pad fused into A-loader): 64m x 4co = 256 blocks x 4 waves
    conv2_fused<<<256, 256, 0, stream>>>(conv1out, st1, g1, b1, wT2, conv2out, st2);

    // conv3 (BN2+lrelu+pad fused into A-loader): 32m x 8co = 256 blocks x 2 waves
    conv3_fused<<<256, 128, 0, stream>>>(conv2out, st2, g2, b2, wT3, conv3out, st3);

    // BN3 finalize + lrelu + NHWC->NCHW bf16 (conv4 input)
    bn_nchw_kernel<<<4096, 256, 0, stream>>>(conv3out, st3, g3, b3, a4, 1048576);

    // conv4: [64,16384] x [1024,16384]^T -> [64,1024], split-K=16
    conv4_mfma<<<256, 256, 0, stream>>>(a4, w4, h4);
    stats_part<<<16, 256, 0, stream>>>(h4, st4, 1024, 64, 64, 4);

    // conv5 (inline BN4)
    conv5_kernel<<<64, 256, 0, stream>>>(h4, st4, g4, b4, w5, b5, (float*)d_out);
}

// Round 9
// 272.993 us; speedup vs baseline: 1.2112x; 1.2112x over previous
//
#include <hip/hip_runtime.h>
#include <hip/hip_bf16.h>

#define NEG 0.01f
#define EPS 1e-5f

typedef __attribute__((ext_vector_type(8))) short short8;
typedef __attribute__((ext_vector_type(4))) float floatx4;

__device__ inline unsigned short f2bf(float f) {
    __hip_bfloat16 h = __float2bfloat16(f);
    union { __hip_bfloat16 h; unsigned short u; } cv; cv.h = h;
    return cv.u;
}

// ---------------------------------------------------------------- render ----
// Writes padded NHWC bf16 [64][68][68][16] INCLUDING zero borders + ch14/15.
// XCD-aligned: XCD k (= blockIdx%8, HW round-robin) renders batches [8k,8k+8)
// so conv1's swizzled XCD k reads its A from the LOCAL L2 (producer/consumer
// co-location; linear grids put the writer's lines in a REMOTE XCD L2).
__global__ __launch_bounds__(256) void render_kernel(const float* __restrict__ in,
                                                     unsigned short* __restrict__ out) {
    int xcd = blockIdx.x & 7, ii = blockIdx.x >> 3;
    int b = xcd * 8 + (ii >> 4);
    int chunk = ii & 15;
    __shared__ float r0[46], r1[46], r2[46], r3[46];
    __shared__ float cls_s[46 * 14];
    int tid = threadIdx.x;
    if (tid < 46) {
        const float* p = in + ((size_t)b * 46 + tid) * 18 + 14;
        float x = p[0] * 64.f, y = p[1] * 64.f, w = p[2] * 64.f, h = p[3] * 64.f;
        r0[tid] = x - 0.5f * w; r1[tid] = x + 0.5f * w;
        r2[tid] = y - 0.5f * h; r3[tid] = y + 0.5f * h;
    }
    for (int idx = tid; idx < 46 * 14; idx += 256) {
        int n = idx / 14, c = idx % 14;
        cls_s[idx] = in[((size_t)b * 46 + n) * 18 + c];
    }
    __syncthreads();
    // border zeroing: 528 border px, 33 per block
    if (tid < 33) {
        int j = chunk * 33 + tid;
        if (j < 528) {
            int y, x;
            if (j < 136) { y = j / 68; x = j - y * 68; }
            else if (j < 272) { int t = j - 136; int yy = t / 68; y = 66 + yy; x = t - yy * 68; }
            else { int t = j - 272; y = 2 + (t >> 2); int k = t & 3; x = (k < 2) ? k : 64 + k; }
            size_t zb = (((size_t)b * 68 + y) * 68 + x) * 16;
            short8 z;
#pragma unroll
            for (int i = 0; i < 8; ++i) z[i] = 0;
            *(short8*)(out + zb) = z;
            *(short8*)(out + zb + 8) = z;
        }
    }
    int pix = chunk * 256 + tid;
    float cx = (float)(pix & 63);
    float cy = (float)(pix >> 6);
    float acc[14];
#pragma unroll
    for (int c = 0; c < 14; ++c) acc[c] = 0.f;
    for (int n = 0; n < 46; ++n) {
        float x0 = r0[n], x1 = r1[n], y0 = r2[n], y1 = r3[n];
        float by = fminf(fmaxf(cy - y0, 0.f), 1.f) * fminf(fmaxf(y1 - cy, 0.f), 1.f);
        float bx = fminf(fmaxf(cx - x0, 0.f), 1.f) * fminf(fmaxf(x1 - cx, 0.f), 1.f);
        float kx0 = fmaxf(1.f - fabsf(cx - x0), 0.f);
        float kx1 = fmaxf(1.f - fabsf(cx - x1), 0.f);
        float ky0 = fmaxf(1.f - fabsf(cy - y0), 0.f);
        float ky1 = fmaxf(1.f - fabsf(cy - y1), 0.f);
        float r = fmaxf(fmaxf(kx0 * by, kx1 * by), fmaxf(ky0 * bx, ky1 * bx));
        if (r > 0.f) {
#pragma unroll
            for (int c = 0; c < 14; ++c) acc[c] = fmaf(cls_s[n * 14 + c], r, acc[c]);
        }
    }
    size_t obase = (((size_t)b * 68 + ((pix >> 6) + 2)) * 68 + ((pix & 63) + 2)) * 16;
    short8 v0, v1;
#pragma unroll
    for (int i = 0; i < 8; ++i) v0[i] = (short)f2bf(acc[i]);
#pragma unroll
    for (int i = 0; i < 6; ++i) v1[i] = (short)f2bf(acc[8 + i]);
    v1[6] = 0; v1[7] = 0;
    *(short8*)(out + obase) = v0;
    *(short8*)(out + obase + 8) = v1;
}

// ------------------------------------------- merged weight transform --------
__global__ __launch_bounds__(256) void wtrans_all(const float* __restrict__ w1,
                                                  const float* __restrict__ w2,
                                                  const float* __restrict__ w3,
                                                  unsigned short* __restrict__ wT1,
                                                  unsigned short* __restrict__ wT2,
                                                  unsigned short* __restrict__ wT3) {
    int idx = blockIdx.x * 256 + threadIdx.x;
    const float* w; unsigned short* wT; int CIN, CPLOG, SUB, COLOG;
    if (idx < 30720) { w = w1; wT = wT1; CIN = 14; CPLOG = 4; SUB = 3; COLOG = 6; }
    else if (idx < 235520) { idx -= 30720; w = w2; wT = wT2; CIN = 64; CPLOG = 6; SUB = 10; COLOG = 7; }
    else if (idx < 1054720) { idx -= 235520; w = w3; wT = wT3; CIN = 128; CPLOG = 7; SUB = 20; COLOG = 8; }
    else return;
    int kk = idx & 31;
    int co = (idx >> 5) & ((1 << COLOG) - 1);
    int s = idx >> (5 + COLOG);
    int kh = s / SUB, sub = s - kh * SUB;
    int kidx = sub * 32 + kk;
    int kw = kidx >> CPLOG;
    int ci = kidx & ((1 << CPLOG) - 1);
    float v = (kw < 5 && ci < CIN) ? w[((size_t)(co * CIN + ci) * 5 + kh) * 5 + kw] : 0.f;
    wT[idx] = f2bf(v);
}

// ------------------------------------------- implicit-GEMM MFMA conv --------
// (verified R4 kernel, unchanged)
template <int CP, int COUT, int HP, int LOG_OHW, int LOG_OW, int SUB,
          int NCO, int NT, int CH, int NW>
__global__ __launch_bounds__(NW * 64) void conv_mfma(
        const unsigned short* __restrict__ inP,
        const unsigned short* __restrict__ wT,
        float* __restrict__ outX,
        float* __restrict__ stacc) {
    constexpr int NSTEP = 5 * SUB;
    constexpr int NCHUNK = NSTEP / CH;
    constexpr int COT = NT * 16;
    constexpr int NSTG = (CH * COT * 4) / (NW * 64);
    static_assert(NSTEP % CH == 0, "CH must divide NSTEP");
    static_assert((CH * COT * 4) % (NW * 64) == 0, "staging must tile evenly");
    __shared__ short Bs[2][CH][COT][32];
    __shared__ float sred[NW][2][COT];
    int tid = threadIdx.x;
    int wave = tid >> 6, lane = tid & 63, q = lane >> 4, l16 = lane & 15;
    // XCD swizzle (grid % 8 == 0 for all launches)
    int cpx = gridDim.x >> 3;
    int lb = (blockIdx.x & 7) * cpx + (blockIdx.x >> 3);
    int bm = lb / NCO, bco = lb % NCO;

    const short* aB[4];
#pragma unroll
    for (int f = 0; f < 4; ++f) {
        int m = bm * (NW * 64) + wave * 64 + f * 16 + l16;
        int b = m >> LOG_OHW;
        int ohw = m & ((1 << LOG_OHW) - 1);
        int oh = ohw >> LOG_OW, ow = ohw & ((1 << LOG_OW) - 1);
        aB[f] = (const short*)inP + ((size_t)((b * HP + 2 * oh) * HP + 2 * ow)) * CP + q * 8;
    }
    const short* bgbase = (const short*)wT + (size_t)bco * COT * 32;

    floatx4 acc[4][NT];
#pragma unroll
    for (int f = 0; f < 4; ++f)
#pragma unroll
        for (int nt = 0; nt < NT; ++nt) acc[f][nt] = (floatx4){0.f, 0.f, 0.f, 0.f};

    short8 nb[NSTG];
    // stage chunk 0
#pragma unroll
    for (int i = 0; i < NSTG; ++i) {
        int v = tid + i * NW * 64;
        int s = v / (COT * 4);
        int rem = v - s * (COT * 4);
        nb[i] = *(const short8*)(bgbase + ((size_t)s * COUT) * 32 + rem * 8);
    }
#pragma unroll
    for (int i = 0; i < NSTG; ++i) {
        int v = tid + i * NW * 64;
        int s = v / (COT * 4);
        int rem = v - s * (COT * 4);
        *(short8*)((short*)&Bs[0][s][0][0] + rem * 8) = nb[i];
    }
    __syncthreads();

    for (int chunk = 0; chunk < NCHUNK; ++chunk) {
        int cur = chunk & 1;
        if (chunk + 1 < NCHUNK) {
            int step0 = (chunk + 1) * CH;
#pragma unroll
            for (int i = 0; i < NSTG; ++i) {
                int v = tid + i * NW * 64;
                int s = v / (COT * 4);
                int rem = v - s * (COT * 4);
                nb[i] = *(const short8*)(bgbase + ((size_t)(step0 + s) * COUT) * 32 + rem * 8);
            }
        }
#pragma unroll
        for (int s = 0; s < CH; ++s) {
            int step = chunk * CH + s;
            int kh = step / SUB, sub = step - kh * SUB;
            short8 af[4];
#pragma unroll
            for (int f = 0; f < 4; ++f)
                af[f] = *(const short8*)(aB[f] + (size_t)(kh * HP) * CP + sub * 32);
#pragma unroll
            for (int nt = 0; nt < NT; ++nt) {
                short8 bf = *(const short8*)&Bs[cur][s][nt * 16 + l16][q * 8];
#pragma unroll
                for (int f = 0; f < 4; ++f)
                    acc[f][nt] = __builtin_amdgcn_mfma_f32_16x16x32_bf16(af[f], bf, acc[f][nt], 0, 0, 0);
            }
        }
        if (chunk + 1 < NCHUNK) {
#pragma unroll
            for (int i = 0; i < NSTG; ++i) {
                int v = tid + i * NW * 64;
                int s = v / (COT * 4);
                int rem = v - s * (COT * 4);
                *(short8*)((short*)&Bs[cur ^ 1][s][0][0] + rem * 8) = nb[i];
            }
            __syncthreads();
        }
    }
    // output
#pragma unroll
    for (int f = 0; f < 4; ++f)
#pragma unroll
        for (int nt = 0; nt < NT; ++nt)
#pragma unroll
            for (int rg = 0; rg < 4; ++rg) {
                int mg = bm * (NW * 64) + wave * 64 + f * 16 + q * 4 + rg;
                int co = bco * COT + nt * 16 + l16;
                outX[(size_t)mg * COUT + co] = acc[f][nt][rg];
            }
    // fused BN stats: wave shfl-reduce -> LDS -> one atomic per co per block
#pragma unroll
    for (int nt = 0; nt < NT; ++nt) {
        float s = 0.f, s2 = 0.f;
#pragma unroll
        for (int f = 0; f < 4; ++f)
#pragma unroll
            for (int rg = 0; rg < 4; ++rg) {
                float v = acc[f][nt][rg];
                s += v; s2 = fmaf(v, v, s2);
            }
        s += __shfl_xor(s, 16); s += __shfl_xor(s, 32);
        s2 += __shfl_xor(s2, 16); s2 += __shfl_xor(s2, 32);
        if (q == 0) {
            sred[wave][0][nt * 16 + l16] = s;
            sred[wave][1][nt * 16 + l16] = s2;
        }
    }
    __syncthreads();
    if (tid < COT) {
        float ts = 0.f, ts2 = 0.f;
#pragma unroll
        for (int w = 0; w < NW; ++w) { ts += sred[w][0][tid]; ts2 += sred[w][1][tid]; }
        atomicAdd(&stacc[bco * COT + tid], ts);
        atomicAdd(&stacc[COUT + bco * COT + tid], ts2);
    }
}

// --------------------------------------------------- conv4 split-K GEMM -----
__global__ __launch_bounds__(256) void conv4_mfma(const unsigned short* __restrict__ A,
                                                  const float* __restrict__ w4,
                                                  float* __restrict__ h4) {
    constexpr int CH = 4, NCHUNK = 8;
    __shared__ short Bs[CH][64][40];
    int tid = threadIdx.x;
    int bco = blockIdx.x & 15;
    int ks = blockIdx.x >> 4;
    int wave = tid >> 6, lane = tid & 63, q = lane >> 4, l16 = lane & 15;
    const short* aBase = (const short*)A + (size_t)(wave * 16 + l16) * 16384 + ks * 1024 + q * 8;
    int r = tid >> 2, cc = tid & 3;
    const float* bg = w4 + (size_t)(bco * 64 + r) * 16384 + ks * 1024 + cc * 8;

    floatx4 acc[4];
#pragma unroll
    for (int nt = 0; nt < 4; ++nt) acc[nt] = (floatx4){0.f, 0.f, 0.f, 0.f};

    short8 nb[CH];
#pragma unroll
    for (int s = 0; s < CH; ++s) {
        float4 b0 = *(const float4*)(bg + s * 32);
        float4 b1 = *(const float4*)(bg + s * 32 + 4);
        nb[s][0] = (short)f2bf(b0.x); nb[s][1] = (short)f2bf(b0.y);
        nb[s][2] = (short)f2bf(b0.z); nb[s][3] = (short)f2bf(b0.w);
        nb[s][4] = (short)f2bf(b1.x); nb[s][5] = (short)f2bf(b1.y);
        nb[s][6] = (short)f2bf(b1.z); nb[s][7] = (short)f2bf(b1.w);
    }
#pragma unroll
    for (int s = 0; s < CH; ++s) *(short8*)&Bs[s][r][cc * 8] = nb[s];
    __syncthreads();

    for (int chunk = 0; chunk < NCHUNK; ++chunk) {
        bool has_next = (chunk + 1 < NCHUNK);
        if (has_next) {
#pragma unroll
            for (int s = 0; s < CH; ++s) {
                int step = (chunk + 1) * CH + s;
                float4 b0 = *(const float4*)(bg + step * 32);
                float4 b1 = *(const float4*)(bg + step * 32 + 4);
                nb[s][0] = (short)f2bf(b0.x); nb[s][1] = (short)f2bf(b0.y);
                nb[s][2] = (short)f2bf(b0.z); nb[s][3] = (short)f2bf(b0.w);
                nb[s][4] = (short)f2bf(b1.x); nb[s][5] = (short)f2bf(b1.y);
                nb[s][6] = (short)f2bf(b1.z); nb[s][7] = (short)f2bf(b1.w);
            }
        }
#pragma unroll
        for (int s = 0; s < CH; ++s) {
            int step = chunk * CH + s;
            short8 af = *(const short8*)(aBase + step * 32);
#pragma unroll
            for (int nt = 0; nt < 4; ++nt) {
                short8 bf = *(const short8*)&Bs[s][nt * 16 + l16][q * 8];
                acc[nt] = __builtin_amdgcn_mfma_f32_16x16x32_bf16(af, bf, acc[nt], 0, 0, 0);
            }
        }
        if (has_next) {
            __syncthreads();
#pragma unroll
            for (int s = 0; s < CH; ++s) *(short8*)&Bs[s][r][cc * 8] = nb[s];
            __syncthreads();
        }
    }
#pragma unroll
    for (int nt = 0; nt < 4; ++nt) {
#pragma unroll
        for (int rg = 0; rg < 4; ++rg) {
            int mg = wave * 16 + q * 4 + rg;
            int co = bco * 64 + nt * 16 + l16;
            atomicAdd(&h4[(size_t)mg * 1024 + co], acc[nt][rg]);
        }
    }
}

// ----------------------------------------------------------- batch stats ----
__global__ __launch_bounds__(256) void stats_part(const float* __restrict__ X,
                                                  float* __restrict__ acc,
                                                  int CO, int R, int RPB, int CGLOG) {
    int tid = threadIdx.x;
    int cg = blockIdx.x & ((1 << CGLOG) - 1);
    int rb = blockIdx.x >> CGLOG;
    int c = (cg << 6) + (tid & 63);
    int w = tid >> 6;
    float s = 0.f, s2 = 0.f;
    int rend = min(R, (rb + 1) * RPB);
    for (int r = rb * RPB + w; r < rend; r += 4) {
        float v = X[(size_t)r * CO + c];
        s += v; s2 += v * v;
    }
    __shared__ float ls[4][64], ls2[4][64];
    ls[w][tid & 63] = s; ls2[w][tid & 63] = s2;
    __syncthreads();
    if (tid < 64) {
        float ts = ls[0][tid] + ls[1][tid] + ls[2][tid] + ls[3][tid];
        float ts2 = ls2[0][tid] + ls2[1][tid] + ls2[2][tid] + ls2[3][tid];
        int cc = (cg << 6) + tid;
        atomicAdd(&acc[cc], ts);
        atomicAdd(&acc[CO + cc], ts2);
    }
}

// ------------------- BN(inline finalize) + lrelu + pad + bf16 (NHWC) --------
// XCD-aligned grid swizzle: XCD k (= blockIdx%8) processes the contiguous
// element range [k*total/8, (k+1)*total/8) == batches [8k,8k+8), matching the
// conv consumer's swizzled A-read range -> handoff stays in the local L2.
__global__ __launch_bounds__(256) void bnpad_kernel(const float* __restrict__ X,
                                                    const float* __restrict__ stacc,
                                                    const float* __restrict__ g,
                                                    const float* __restrict__ bb,
                                                    unsigned short* __restrict__ out,
                                                    int CO_LOG, int OH, int OHP,
                                                    float invN, int total) {
    int nb8 = gridDim.x >> 3;
    int sb = (blockIdx.x & 7) * nb8 + (blockIdx.x >> 3);
    int idx = sb * 256 + threadIdx.x;
    if (idx >= total) return;
    int CO = 1 << CO_LOG;
    int c = idx & (CO - 1);
    float mean = stacc[c] * invN;
    float var = fmaxf(stacc[CO + c] * invN - mean * mean, 0.f);
    float sc = g[c] * rsqrtf(var + EPS);
    float sh = bb[c] - mean * sc;
    int t = idx >> CO_LOG;
    int x = t % OHP; t /= OHP;
    int y = t % OHP; int b = t / OHP;
    unsigned short v = 0;
    if (y >= 2 && y < OH + 2 && x >= 2 && x < OH + 2) {
        float f = X[(((size_t)(b * OH + (y - 2)) * OH + (x - 2)) << CO_LOG) + c];
        f = f * sc + sh;
        f = f >= 0.f ? f : NEG * f;
        v = f2bf(f);
    }
    out[idx] = v;
}

// -------- BN(inline finalize) + lrelu + bf16, NHWC -> NCHW (conv4 input) ----
// Same XCD-aligned swizzle (consumer conv4 is batch-global; swizzle is
// harmless there but keeps conv3out reads local to the writer's XCD).
__global__ __launch_bounds__(256) void bn_nchw_kernel(const float* __restrict__ X,
                                                      const float* __restrict__ stacc,
                                                      const float* __restrict__ g,
                                                      const float* __restrict__ bb,
                                                      unsigned short* __restrict__ out,
                                                      int total) {
    int nb8 = gridDim.x >> 3;
    int sb = (blockIdx.x & 7) * nb8 + (blockIdx.x >> 3);
    int idx = sb * 256 + threadIdx.x;
    if (idx >= total) return;
    int hw = idx & 63;
    int ci = (idx >> 6) & 255;
    int b = idx >> 14;
    float mean = stacc[ci] * (1.f / 4096.f);
    float var = fmaxf(stacc[256 + ci] * (1.f / 4096.f) - mean * mean, 0.f);
    float sc = g[ci] * rsqrtf(var + EPS);
    float sh = bb[ci] - mean * sc;
    float f = X[((size_t)(b * 64 + hw)) * 256 + ci] * sc + sh;
    f = f >= 0.f ? f : NEG * f;
    out[idx] = f2bf(f);
}

// -------------------------------------- conv5 (inline BN4 finalize) ---------
__global__ __launch_bounds__(256) void conv5_kernel(const float* __restrict__ X,
                                                    const float* __restrict__ stacc,
                                                    const float* __restrict__ g,
                                                    const float* __restrict__ bb,
                                                    const float* __restrict__ w5,
                                                    const float* __restrict__ b5,
                                                    float* __restrict__ out) {
    int b = blockIdx.x, tid = threadIdx.x;
    float s = 0.f;
    for (int c = tid; c < 1024; c += 256) {
        float mean = stacc[c] * (1.f / 64.f);
        float var = fmaxf(stacc[1024 + c] * (1.f / 64.f) - mean * mean, 0.f);
        float sc = g[c] * rsqrtf(var + EPS);
        float sh = bb[c] - mean * sc;
        float f = X[(size_t)b * 1024 + c] * sc + sh;
        f = f >= 0.f ? f : NEG * f;
        s = fmaf(f, w5[c], s);
    }
#pragma unroll
    for (int off = 32; off > 0; off >>= 1) s += __shfl_down(s, off);
    __shared__ float ls[4];
    if ((tid & 63) == 0) ls[tid >> 6] = s;
    __syncthreads();
    if (tid == 0) out[b] = ls[0] + ls[1] + ls[2] + ls[3] + b5[0];
}

// ----------------------------------------------------------------- launch ---
extern "C" void kernel_launch(void* const* d_in, const int* in_sizes, int n_in,
                              void* d_out, int out_size, void* d_ws, size_t ws_size,
                              hipStream_t stream) {
    (void)in_sizes; (void)n_in; (void)out_size; (void)ws_size;
    const float* input_data = (const float*)d_in[0];
    const float* w1 = (const float*)d_in[2];
    const float* g1 = (const float*)d_in[3];
    const float* b1 = (const float*)d_in[4];
    const float* w2 = (const float*)d_in[5];
    const float* g2 = (const float*)d_in[6];
    const float* b2 = (const float*)d_in[7];
    const float* w3 = (const float*)d_in[8];
    const float* g3 = (const float*)d_in[9];
    const float* b3 = (const float*)d_in[10];
    const float* w4 = (const float*)d_in[11];
    const float* g4 = (const float*)d_in[12];
    const float* b4 = (const float*)d_in[13];
    const float* w5 = (const float*)d_in[14];
    const float* b5 = (const float*)d_in[15];

    char* ws = (char*)d_ws;
    float* regA = (float*)ws;               // 16.8 MB: conv1out / conv3out
    char* wsB = ws + 16777216;              // 10.7 MB: pad1 / pad2
    char* wsC = wsB + 10616832;             // 9.5 MB: rendered / conv2out / a4
    char* wsD = wsC + 9469952;
    float* h4  = (float*)wsD;                               // 262,144 B
    float* st1 = (float*)(wsD + 262144);                    // 512 B  (64*2)
    float* st2 = (float*)(wsD + 262656);                    // 1024 B (128*2)
    float* st3 = (float*)(wsD + 263680);                    // 2048 B (256*2)
    float* st4 = (float*)(wsD + 265728);                    // 8192 B (1024*2)
    unsigned short* wT1 = (unsigned short*)(wsD + 274432);  // 61,440 B
    unsigned short* wT2 = (unsigned short*)(wsD + 335872);  // 409,600 B
    unsigned short* wT3 = (unsigned short*)(wsD + 745472);  // 1,638,400 B

    unsigned short* rendered = (unsigned short*)wsC;
    float* conv1out = regA;
    unsigned short* pad1 = (unsigned short*)wsB;
    float* conv2out = (float*)wsC;
    unsigned short* pad2 = (unsigned short*)wsB;
    float* conv3out = regA;
    unsigned short* a4 = (unsigned short*)wsC;

    // one memset covers h4 + all stat accumulators
    hipMemsetAsync(wsD, 0, 273920, stream);
    wtrans_all<<<4120, 256, 0, stream>>>(w1, w2, w3, wT1, wT2, wT3);
    render_kernel<<<1024, 256, 0, stream>>>(input_data, rendered);

    // conv1: [65536,480]x[480,64] — 256 blocks x 4 waves, NT=4, CH=5 (3 chunks)
    conv_mfma<16, 64, 68, 10, 5, 3, 1, 4, 5, 4><<<256, 256, 0, stream>>>(rendered, wT1, conv1out, st1);
    bnpad_kernel<<<20736, 256, 0, stream>>>(conv1out, st1, g1, b1, pad1, 6, 32, 36, 1.f / 65536.f, 5308416);

    // conv2: [16384,1600]x[1600,128] — 64m x 4co = 256 blocks, NT=2, CH=10 (5 chunks)
    conv_mfma<64, 128, 36, 8, 4, 10, 4, 2, 10, 4><<<256, 256, 0, stream>>>(pad1, wT2, conv2out, st2);
    bnpad_kernel<<<12800, 256, 0, stream>>>(conv2out, st2, g2, b2, pad2, 7, 16, 20, 1.f / 16384.f, 3276800);

    // conv3: [4096,3200]x[3200,256] — 32m x 8co = 256 blocks of 2 waves, NT=2, CH=10
    conv_mfma<128, 256, 20, 6, 3, 20, 8, 2, 10, 2><<<256, 128, 0, stream>>>(pad2, wT3, conv3out, st3);
    bn_nchw_kernel<<<4096, 256, 0, stream>>>(conv3out, st3, g3, b3, a4, 1048576);

    // conv4: [64,16384] x [1024,16384]^T -> [64,1024], split-K=16
    conv4_mfma<<<256, 256, 0, stream>>>(a4, w4, h4);
    stats_part<<<16, 256, 0, stream>>>(h4, st4, 1024, 64, 64, 4);

    // conv5 (inline BN4)
    conv5_kernel<<<64, 256, 0, stream>>>(h4, st4, g4, b4, w5, b5, (float*)d_out);
}

// Round 10
// 260.738 us; speedup vs baseline: 1.2681x; 1.0470x over previous
//
#include <hip/hip_runtime.h>
#include <hip/hip_bf16.h>

#define NEG 0.01f
#define EPS 1e-5f

typedef __attribute__((ext_vector_type(8))) short short8;
typedef __attribute__((ext_vector_type(4))) float floatx4;

__device__ inline unsigned short f2bf(float f) {
    __hip_bfloat16 h = __float2bfloat16(f);
    union { __hip_bfloat16 h; unsigned short u; } cv; cv.h = h;
    return cv.u;
}

// ---------------------------------------------------------------- render ----
// Writes padded NHWC bf16 [64][68][68][16] INCLUDING zero borders + ch14/15.
// (conv1's A-loads on this layout are already fully coalesced: 32B pixels x
// stride-2 = 64B per l16, q fills the gap -> one contiguous 1KB per wave.)
__global__ __launch_bounds__(256) void render_kernel(const float* __restrict__ in,
                                                     unsigned short* __restrict__ out) {
    int xcd = blockIdx.x & 7, ii = blockIdx.x >> 3;
    int b = xcd * 8 + (ii >> 4);
    int chunk = ii & 15;
    __shared__ float r0[46], r1[46], r2[46], r3[46];
    __shared__ float cls_s[46 * 14];
    int tid = threadIdx.x;
    if (tid < 46) {
        const float* p = in + ((size_t)b * 46 + tid) * 18 + 14;
        float x = p[0] * 64.f, y = p[1] * 64.f, w = p[2] * 64.f, h = p[3] * 64.f;
        r0[tid] = x - 0.5f * w; r1[tid] = x + 0.5f * w;
        r2[tid] = y - 0.5f * h; r3[tid] = y + 0.5f * h;
    }
    for (int idx = tid; idx < 46 * 14; idx += 256) {
        int n = idx / 14, c = idx % 14;
        cls_s[idx] = in[((size_t)b * 46 + n) * 18 + c];
    }
    __syncthreads();
    if (tid < 33) {
        int j = chunk * 33 + tid;
        if (j < 528) {
            int y, x;
            if (j < 136) { y = j / 68; x = j - y * 68; }
            else if (j < 272) { int t = j - 136; int yy = t / 68; y = 66 + yy; x = t - yy * 68; }
            else { int t = j - 272; y = 2 + (t >> 2); int k = t & 3; x = (k < 2) ? k : 64 + k; }
            size_t zb = (((size_t)b * 68 + y) * 68 + x) * 16;
            short8 z;
#pragma unroll
            for (int i = 0; i < 8; ++i) z[i] = 0;
            *(short8*)(out + zb) = z;
            *(short8*)(out + zb + 8) = z;
        }
    }
    int pix = chunk * 256 + tid;
    float cx = (float)(pix & 63);
    float cy = (float)(pix >> 6);
    float acc[14];
#pragma unroll
    for (int c = 0; c < 14; ++c) acc[c] = 0.f;
    for (int n = 0; n < 46; ++n) {
        float x0 = r0[n], x1 = r1[n], y0 = r2[n], y1 = r3[n];
        float by = fminf(fmaxf(cy - y0, 0.f), 1.f) * fminf(fmaxf(y1 - cy, 0.f), 1.f);
        float bx = fminf(fmaxf(cx - x0, 0.f), 1.f) * fminf(fmaxf(x1 - cx, 0.f), 1.f);
        float kx0 = fmaxf(1.f - fabsf(cx - x0), 0.f);
        float kx1 = fmaxf(1.f - fabsf(cx - x1), 0.f);
        float ky0 = fmaxf(1.f - fabsf(cy - y0), 0.f);
        float ky1 = fmaxf(1.f - fabsf(cy - y1), 0.f);
        float r = fmaxf(fmaxf(kx0 * by, kx1 * by), fmaxf(ky0 * bx, ky1 * bx));
        if (r > 0.f) {
#pragma unroll
            for (int c = 0; c < 14; ++c) acc[c] = fmaf(cls_s[n * 14 + c], r, acc[c]);
        }
    }
    size_t obase = (((size_t)b * 68 + ((pix >> 6) + 2)) * 68 + ((pix & 63) + 2)) * 16;
    short8 v0, v1;
#pragma unroll
    for (int i = 0; i < 8; ++i) v0[i] = (short)f2bf(acc[i]);
#pragma unroll
    for (int i = 0; i < 6; ++i) v1[i] = (short)f2bf(acc[8 + i]);
    v1[6] = 0; v1[7] = 0;
    *(short8*)(out + obase) = v0;
    *(short8*)(out + obase + 8) = v1;
}

// ------------------------------------------- merged weight transform --------
__global__ __launch_bounds__(256) void wtrans_all(const float* __restrict__ w1,
                                                  const float* __restrict__ w2,
                                                  const float* __restrict__ w3,
                                                  unsigned short* __restrict__ wT1,
                                                  unsigned short* __restrict__ wT2,
                                                  unsigned short* __restrict__ wT3) {
    int idx = blockIdx.x * 256 + threadIdx.x;
    const float* w; unsigned short* wT; int CIN, CPLOG, SUB, COLOG;
    if (idx < 30720) { w = w1; wT = wT1; CIN = 14; CPLOG = 4; SUB = 3; COLOG = 6; }
    else if (idx < 235520) { idx -= 30720; w = w2; wT = wT2; CIN = 64; CPLOG = 6; SUB = 10; COLOG = 7; }
    else if (idx < 1054720) { idx -= 235520; w = w3; wT = wT3; CIN = 128; CPLOG = 7; SUB = 20; COLOG = 8; }
    else return;
    int kk = idx & 31;
    int co = (idx >> 5) & ((1 << COLOG) - 1);
    int s = idx >> (5 + COLOG);
    int kh = s / SUB, sub = s - kh * SUB;
    int kidx = sub * 32 + kk;
    int kw = kidx >> CPLOG;
    int ci = kidx & ((1 << CPLOG) - 1);
    float v = (kw < 5 && ci < CIN) ? w[((size_t)(co * CIN + ci) * 5 + kh) * 5 + kw] : 0.f;
    wT[idx] = f2bf(v);
}

// ------------------------------------------- implicit-GEMM MFMA conv --------
// (verified R4 kernel, unchanged; used for conv1 whose A is coalesced)
template <int CP, int COUT, int HP, int LOG_OHW, int LOG_OW, int SUB,
          int NCO, int NT, int CH, int NW>
__global__ __launch_bounds__(NW * 64) void conv_mfma(
        const unsigned short* __restrict__ inP,
        const unsigned short* __restrict__ wT,
        float* __restrict__ outX,
        float* __restrict__ stacc) {
    constexpr int NSTEP = 5 * SUB;
    constexpr int NCHUNK = NSTEP / CH;
    constexpr int COT = NT * 16;
    constexpr int NSTG = (CH * COT * 4) / (NW * 64);
    static_assert(NSTEP % CH == 0, "CH must divide NSTEP");
    __shared__ short Bs[2][CH][COT][32];
    __shared__ float sred[NW][2][COT];
    int tid = threadIdx.x;
    int wave = tid >> 6, lane = tid & 63, q = lane >> 4, l16 = lane & 15;
    int cpx = gridDim.x >> 3;
    int lb = (blockIdx.x & 7) * cpx + (blockIdx.x >> 3);
    int bm = lb / NCO, bco = lb % NCO;

    const short* aB[4];
#pragma unroll
    for (int f = 0; f < 4; ++f) {
        int m = bm * (NW * 64) + wave * 64 + f * 16 + l16;
        int b = m >> LOG_OHW;
        int ohw = m & ((1 << LOG_OHW) - 1);
        int oh = ohw >> LOG_OW, ow = ohw & ((1 << LOG_OW) - 1);
        aB[f] = (const short*)inP + ((size_t)((b * HP + 2 * oh) * HP + 2 * ow)) * CP + q * 8;
    }
    const short* bgbase = (const short*)wT + (size_t)bco * COT * 32;

    floatx4 acc[4][NT];
#pragma unroll
    for (int f = 0; f < 4; ++f)
#pragma unroll
        for (int nt = 0; nt < NT; ++nt) acc[f][nt] = (floatx4){0.f, 0.f, 0.f, 0.f};

    short8 nb[NSTG];
#pragma unroll
    for (int i = 0; i < NSTG; ++i) {
        int v = tid + i * NW * 64;
        int s = v / (COT * 4);
        int rem = v - s * (COT * 4);
        nb[i] = *(const short8*)(bgbase + ((size_t)s * COUT) * 32 + rem * 8);
    }
#pragma unroll
    for (int i = 0; i < NSTG; ++i) {
        int v = tid + i * NW * 64;
        int s = v / (COT * 4);
        int rem = v - s * (COT * 4);
        *(short8*)((short*)&Bs[0][s][0][0] + rem * 8) = nb[i];
    }
    __syncthreads();

    for (int chunk = 0; chunk < NCHUNK; ++chunk) {
        int cur = chunk & 1;
        if (chunk + 1 < NCHUNK) {
            int step0 = (chunk + 1) * CH;
#pragma unroll
            for (int i = 0; i < NSTG; ++i) {
                int v = tid + i * NW * 64;
                int s = v / (COT * 4);
                int rem = v - s * (COT * 4);
                nb[i] = *(const short8*)(bgbase + ((size_t)(step0 + s) * COUT) * 32 + rem * 8);
            }
        }
#pragma unroll
        for (int s = 0; s < CH; ++s) {
            int step = chunk * CH + s;
            int kh = step / SUB, sub = step - kh * SUB;
            short8 af[4];
#pragma unroll
            for (int f = 0; f < 4; ++f)
                af[f] = *(const short8*)(aB[f] + (size_t)(kh * HP) * CP + sub * 32);
#pragma unroll
            for (int nt = 0; nt < NT; ++nt) {
                short8 bf = *(const short8*)&Bs[cur][s][nt * 16 + l16][q * 8];
#pragma unroll
                for (int f = 0; f < 4; ++f)
                    acc[f][nt] = __builtin_amdgcn_mfma_f32_16x16x32_bf16(af[f], bf, acc[f][nt], 0, 0, 0);
            }
        }
        if (chunk + 1 < NCHUNK) {
#pragma unroll
            for (int i = 0; i < NSTG; ++i) {
                int v = tid + i * NW * 64;
                int s = v / (COT * 4);
                int rem = v - s * (COT * 4);
                *(short8*)((short*)&Bs[cur ^ 1][s][0][0] + rem * 8) = nb[i];
            }
            __syncthreads();
        }
    }
#pragma unroll
    for (int f = 0; f < 4; ++f)
#pragma unroll
        for (int nt = 0; nt < NT; ++nt)
#pragma unroll
            for (int rg = 0; rg < 4; ++rg) {
                int mg = bm * (NW * 64) + wave * 64 + f * 16 + q * 4 + rg;
                int co = bco * COT + nt * 16 + l16;
                outX[(size_t)mg * COUT + co] = acc[f][nt][rg];
            }
#pragma unroll
    for (int nt = 0; nt < NT; ++nt) {
        float s = 0.f, s2 = 0.f;
#pragma unroll
        for (int f = 0; f < 4; ++f)
#pragma unroll
            for (int rg = 0; rg < 4; ++rg) {
                float v = acc[f][nt][rg];
                s += v; s2 = fmaf(v, v, s2);
            }
        s += __shfl_xor(s, 16); s += __shfl_xor(s, 32);
        s2 += __shfl_xor(s2, 16); s2 += __shfl_xor(s2, 32);
        if (q == 0) {
            sred[wave][0][nt * 16 + l16] = s;
            sred[wave][1][nt * 16 + l16] = s2;
        }
    }
    __syncthreads();
    if (tid < COT) {
        float ts = 0.f, ts2 = 0.f;
#pragma unroll
        for (int w = 0; w < NW; ++w) { ts += sred[w][0][tid]; ts2 += sred[w][1][tid]; }
        atomicAdd(&stacc[bco * COT + tid], ts);
        atomicAdd(&stacc[COUT + bco * COT + tid], ts2);
    }
}

// --------------------- conv on parity-plane A layout (conv2, conv3) ---------
// A layout: [b][py][px][oct32][PH][PH][32ch] bf16 (padding materialized).
// K-step (kh, sub): kw=sub>>KWSH, oct=sub&(OCT-1); plane sel=(kh&1)*2+(kw&1);
// y'=oh+(kh>>1), x'=ow+(kw>>1). Per-lane addr = precomputed (oh*PH+ow)*32+q*8
// + WAVE-UNIFORM step offset (SGPR). Wave load = 16 l16 x 64B stride + q*16B
// = one contiguous 1KB region, 8 fully-used cache lines (was 16 partial lines
// at 256/512B stride on the old padded-NHWC layout). Everything else is the
// verified conv_mfma structure (B LDS staging, swizzle, fused BN stats).
template <int COUT, int PH, int LOG_OHW, int LOG_OW, int SUB,
          int NCO, int NT, int CH, int NW, int KWSH>
__global__ __launch_bounds__(NW * 64) void conv_plane(
        const unsigned short* __restrict__ inP,
        const unsigned short* __restrict__ wT,
        float* __restrict__ outX,
        float* __restrict__ stacc) {
    constexpr int OCT = 1 << KWSH;
    constexpr int NSTEP = 5 * SUB;
    constexpr int NCHUNK = NSTEP / CH;
    constexpr int COT = NT * 16;
    constexpr int NSTG = (CH * COT * 4) / (NW * 64);
    constexpr int PPS = PH * PH * 32;       // shorts per (sel,oct) plane
    static_assert(NSTEP % CH == 0, "CH must divide NSTEP");
    __shared__ short Bs[2][CH][COT][32];
    __shared__ float sred[NW][2][COT];
    int tid = threadIdx.x;
    int wave = tid >> 6, lane = tid & 63, q = lane >> 4, l16 = lane & 15;
    int cpx = gridDim.x >> 3;
    int lb = (blockIdx.x & 7) * cpx + (blockIdx.x >> 3);
    int bm = lb / NCO, bco = lb % NCO;

    const short* aP[4];
#pragma unroll
    for (int f = 0; f < 4; ++f) {
        int m = bm * (NW * 64) + wave * 64 + f * 16 + l16;
        int b = m >> LOG_OHW;
        int ohw = m & ((1 << LOG_OHW) - 1);
        int oh = ohw >> LOG_OW, ow = ohw & ((1 << LOG_OW) - 1);
        aP[f] = (const short*)inP + (size_t)b * (4 * OCT * PPS) + (oh * PH + ow) * 32 + q * 8;
    }
    const short* bgbase = (const short*)wT + (size_t)bco * COT * 32;

    floatx4 acc[4][NT];
#pragma unroll
    for (int f = 0; f < 4; ++f)
#pragma unroll
        for (int nt = 0; nt < NT; ++nt) acc[f][nt] = (floatx4){0.f, 0.f, 0.f, 0.f};

    short8 nb[NSTG];
#pragma unroll
    for (int i = 0; i < NSTG; ++i) {
        int v = tid + i * NW * 64;
        int s = v / (COT * 4);
        int rem = v - s * (COT * 4);
        nb[i] = *(const short8*)(bgbase + ((size_t)s * COUT) * 32 + rem * 8);
    }
#pragma unroll
    for (int i = 0; i < NSTG; ++i) {
        int v = tid + i * NW * 64;
        int s = v / (COT * 4);
        int rem = v - s * (COT * 4);
        *(short8*)((short*)&Bs[0][s][0][0] + rem * 8) = nb[i];
    }
    __syncthreads();

    for (int chunk = 0; chunk < NCHUNK; ++chunk) {
        int cur = chunk & 1;
        if (chunk + 1 < NCHUNK) {
            int step0 = (chunk + 1) * CH;
#pragma unroll
            for (int i = 0; i < NSTG; ++i) {
                int v = tid + i * NW * 64;
                int s = v / (COT * 4);
                int rem = v - s * (COT * 4);
                nb[i] = *(const short8*)(bgbase + ((size_t)(step0 + s) * COUT) * 32 + rem * 8);
            }
        }
#pragma unroll
        for (int s = 0; s < CH; ++s) {
            int step = chunk * CH + s;
            int kh = step / SUB, sub = step - kh * SUB;
            int kw = sub >> KWSH, oct = sub & (OCT - 1);
            // wave-uniform plane offset (compiler scalarizes to SGPR)
            int soff = ((((kh & 1) * 2 + (kw & 1)) * OCT + oct) * PH * PH
                        + (kh >> 1) * PH + (kw >> 1)) * 32;
            short8 af[4];
#pragma unroll
            for (int f = 0; f < 4; ++f)
                af[f] = *(const short8*)(aP[f] + soff);
#pragma unroll
            for (int nt = 0; nt < NT; ++nt) {
                short8 bf = *(const short8*)&Bs[cur][s][nt * 16 + l16][q * 8];
#pragma unroll
                for (int f = 0; f < 4; ++f)
                    acc[f][nt] = __builtin_amdgcn_mfma_f32_16x16x32_bf16(af[f], bf, acc[f][nt], 0, 0, 0);
            }
        }
        if (chunk + 1 < NCHUNK) {
#pragma unroll
            for (int i = 0; i < NSTG; ++i) {
                int v = tid + i * NW * 64;
                int s = v / (COT * 4);
                int rem = v - s * (COT * 4);
                *(short8*)((short*)&Bs[cur ^ 1][s][0][0] + rem * 8) = nb[i];
            }
            __syncthreads();
        }
    }
#pragma unroll
    for (int f = 0; f < 4; ++f)
#pragma unroll
        for (int nt = 0; nt < NT; ++nt)
#pragma unroll
            for (int rg = 0; rg < 4; ++rg) {
                int mg = bm * (NW * 64) + wave * 64 + f * 16 + q * 4 + rg;
                int co = bco * COT + nt * 16 + l16;
                outX[(size_t)mg * COUT + co] = acc[f][nt][rg];
            }
#pragma unroll
    for (int nt = 0; nt < NT; ++nt) {
        float s = 0.f, s2 = 0.f;
#pragma unroll
        for (int f = 0; f < 4; ++f)
#pragma unroll
            for (int rg = 0; rg < 4; ++rg) {
                float v = acc[f][nt][rg];
                s += v; s2 = fmaf(v, v, s2);
            }
        s += __shfl_xor(s, 16); s += __shfl_xor(s, 32);
        s2 += __shfl_xor(s2, 16); s2 += __shfl_xor(s2, 32);
        if (q == 0) {
            sred[wave][0][nt * 16 + l16] = s;
            sred[wave][1][nt * 16 + l16] = s2;
        }
    }
    __syncthreads();
    if (tid < COT) {
        float ts = 0.f, ts2 = 0.f;
#pragma unroll
        for (int w = 0; w < NW; ++w) { ts += sred[w][0][tid]; ts2 += sred[w][1][tid]; }
        atomicAdd(&stacc[bco * COT + tid], ts);
        atomicAdd(&stacc[COUT + bco * COT + tid], ts2);
    }
}

// --------------------------------------------------- conv4 split-K GEMM -----
__global__ __launch_bounds__(256) void conv4_mfma(const unsigned short* __restrict__ A,
                                                  const float* __restrict__ w4,
                                                  float* __restrict__ h4) {
    constexpr int CH = 4, NCHUNK = 8;
    __shared__ short Bs[CH][64][40];
    int tid = threadIdx.x;
    int bco = blockIdx.x & 15;
    int ks = blockIdx.x >> 4;
    int wave = tid >> 6, lane = tid & 63, q = lane >> 4, l16 = lane & 15;
    const short* aBase = (const short*)A + (size_t)(wave * 16 + l16) * 16384 + ks * 1024 + q * 8;
    int r = tid >> 2, cc = tid & 3;
    const float* bg = w4 + (size_t)(bco * 64 + r) * 16384 + ks * 1024 + cc * 8;

    floatx4 acc[4];
#pragma unroll
    for (int nt = 0; nt < 4; ++nt) acc[nt] = (floatx4){0.f, 0.f, 0.f, 0.f};

    short8 nb[CH];
#pragma unroll
    for (int s = 0; s < CH; ++s) {
        float4 b0 = *(const float4*)(bg + s * 32);
        float4 b1 = *(const float4*)(bg + s * 32 + 4);
        nb[s][0] = (short)f2bf(b0.x); nb[s][1] = (short)f2bf(b0.y);
        nb[s][2] = (short)f2bf(b0.z); nb[s][3] = (short)f2bf(b0.w);
        nb[s][4] = (short)f2bf(b1.x); nb[s][5] = (short)f2bf(b1.y);
        nb[s][6] = (short)f2bf(b1.z); nb[s][7] = (short)f2bf(b1.w);
    }
#pragma unroll
    for (int s = 0; s < CH; ++s) *(short8*)&Bs[s][r][cc * 8] = nb[s];
    __syncthreads();

    for (int chunk = 0; chunk < NCHUNK; ++chunk) {
        bool has_next = (chunk + 1 < NCHUNK);
        if (has_next) {
#pragma unroll
            for (int s = 0; s < CH; ++s) {
                int step = (chunk + 1) * CH + s;
                float4 b0 = *(const float4*)(bg + step * 32);
                float4 b1 = *(const float4*)(bg + step * 32 + 4);
                nb[s][0] = (short)f2bf(b0.x); nb[s][1] = (short)f2bf(b0.y);
                nb[s][2] = (short)f2bf(b0.z); nb[s][3] = (short)f2bf(b0.w);
                nb[s][4] = (short)f2bf(b1.x); nb[s][5] = (short)f2bf(b1.y);
                nb[s][6] = (short)f2bf(b1.z); nb[s][7] = (short)f2bf(b1.w);
            }
        }
#pragma unroll
        for (int s = 0; s < CH; ++s) {
            int step = chunk * CH + s;
            short8 af = *(const short8*)(aBase + step * 32);
#pragma unroll
            for (int nt = 0; nt < 4; ++nt) {
                short8 bf = *(const short8*)&Bs[s][nt * 16 + l16][q * 8];
                acc[nt] = __builtin_amdgcn_mfma_f32_16x16x32_bf16(af, bf, acc[nt], 0, 0, 0);
            }
        }
        if (has_next) {
            __syncthreads();
#pragma unroll
            for (int s = 0; s < CH; ++s) *(short8*)&Bs[s][r][cc * 8] = nb[s];
            __syncthreads();
        }
    }
#pragma unroll
    for (int nt = 0; nt < 4; ++nt) {
#pragma unroll
        for (int rg = 0; rg < 4; ++rg) {
            int mg = wave * 16 + q * 4 + rg;
            int co = bco * 64 + nt * 16 + l16;
            atomicAdd(&h4[(size_t)mg * 1024 + co], acc[nt][rg]);
        }
    }
}

// ----------------------------------------------------------- batch stats ----
__global__ __launch_bounds__(256) void stats_part(const float* __restrict__ X,
                                                  float* __restrict__ acc,
                                                  int CO, int R, int RPB, int CGLOG) {
    int tid = threadIdx.x;
    int cg = blockIdx.x & ((1 << CGLOG) - 1);
    int rb = blockIdx.x >> CGLOG;
    int c = (cg << 6) + (tid & 63);
    int w = tid >> 6;
    float s = 0.f, s2 = 0.f;
    int rend = min(R, (rb + 1) * RPB);
    for (int r = rb * RPB + w; r < rend; r += 4) {
        float v = X[(size_t)r * CO + c];
        s += v; s2 += v * v;
    }
    __shared__ float ls[4][64], ls2[4][64];
    ls[w][tid & 63] = s; ls2[w][tid & 63] = s2;
    __syncthreads();
    if (tid < 64) {
        float ts = ls[0][tid] + ls[1][tid] + ls[2][tid] + ls[3][tid];
        float ts2 = ls2[0][tid] + ls2[1][tid] + ls2[2][tid] + ls2[3][tid];
        int cc = (cg << 6) + tid;
        atomicAdd(&acc[cc], ts);
        atomicAdd(&acc[CO + cc], ts2);
    }
}

// ---------- BN(inline finalize) + lrelu + bf16 -> parity-plane layout -------
// out: [b][py][px][oct32][PH][PH][32ch]; pad materialized as zeros in-plane.
// Same quantization point as the old bnpad path (bit-identical values).
// XCD-aligned grid swizzle kept (b outermost -> producer/consumer co-location).
__global__ __launch_bounds__(256) void bnpad_plane(const float* __restrict__ X,
                                                   const float* __restrict__ stacc,
                                                   const float* __restrict__ g,
                                                   const float* __restrict__ bb,
                                                   unsigned short* __restrict__ out,
                                                   int CO_LOG, int OH, int PH,
                                                   int OCTLOG, float invN, int total) {
    int nb8 = gridDim.x >> 3;
    int sb = (blockIdx.x & 7) * nb8 + (blockIdx.x >> 3);
    int idx = sb * 256 + threadIdx.x;
    if (idx >= total) return;
    int CO = 1 << CO_LOG;
    int c32 = idx & 31;
    int t = idx >> 5;
    int xp = t % PH; t /= PH;
    int yp = t % PH; t /= PH;
    int oct = t & ((1 << OCTLOG) - 1); t >>= OCTLOG;
    int px = t & 1, py = (t >> 1) & 1;
    int b = t >> 2;
    int c = (oct << 5) + c32;
    float mean = stacc[c] * invN;
    float var = fmaxf(stacc[CO + c] * invN - mean * mean, 0.f);
    float sc = g[c] * rsqrtf(var + EPS);
    float sh = bb[c] - mean * sc;
    int y = 2 * yp + py - 2, x = 2 * xp + px - 2;
    unsigned short v = 0;
    if ((unsigned)y < (unsigned)OH && (unsigned)x < (unsigned)OH) {
        float f = X[(((size_t)(b * OH + y) * OH + x)) * CO + c];
        f = f * sc + sh;
        f = f >= 0.f ? f : NEG * f;
        v = f2bf(f);
    }
    out[idx] = v;
}

// -------- BN(inline finalize) + lrelu + bf16, NHWC -> NCHW (conv4 input) ----
__global__ __launch_bounds__(256) void bn_nchw_kernel(const float* __restrict__ X,
                                                      const float* __restrict__ stacc,
                                                      const float* __restrict__ g,
                                                      const float* __restrict__ bb,
                                                      unsigned short* __restrict__ out,
                                                      int total) {
    int nb8 = gridDim.x >> 3;
    int sb = (blockIdx.x & 7) * nb8 + (blockIdx.x >> 3);
    int idx = sb * 256 + threadIdx.x;
    if (idx >= total) return;
    int hw = idx & 63;
    int ci = (idx >> 6) & 255;
    int b = idx >> 14;
    float mean = stacc[ci] * (1.f / 4096.f);
    float var = fmaxf(stacc[256 + ci] * (1.f / 4096.f) - mean * mean, 0.f);
    float sc = g[ci] * rsqrtf(var + EPS);
    float sh = bb[ci] - mean * sc;
    float f = X[((size_t)(b * 64 + hw)) * 256 + ci] * sc + sh;
    f = f >= 0.f ? f : NEG * f;
    out[idx] = f2bf(f);
}

// -------------------------------------- conv5 (inline BN4 finalize) ---------
__global__ __launch_bounds__(256) void conv5_kernel(const float* __restrict__ X,
                                                    const float* __restrict__ stacc,
                                                    const float* __restrict__ g,
                                                    const float* __restrict__ bb,
                                                    const float* __restrict__ w5,
                                                    const float* __restrict__ b5,
                                                    float* __restrict__ out) {
    int b = blockIdx.x, tid = threadIdx.x;
    float s = 0.f;
    for (int c = tid; c < 1024; c += 256) {
        float mean = stacc[c] * (1.f / 64.f);
        float var = fmaxf(stacc[1024 + c] * (1.f / 64.f) - mean * mean, 0.f);
        float sc = g[c] * rsqrtf(var + EPS);
        float sh = bb[c] - mean * sc;
        float f = X[(size_t)b * 1024 + c] * sc + sh;
        f = f >= 0.f ? f : NEG * f;
        s = fmaf(f, w5[c], s);
    }
#pragma unroll
    for (int off = 32; off > 0; off >>= 1) s += __shfl_down(s, off);
    __shared__ float ls[4];
    if ((tid & 63) == 0) ls[tid >> 6] = s;
    __syncthreads();
    if (tid == 0) out[b] = ls[0] + ls[1] + ls[2] + ls[3] + b5[0];
}

// ----------------------------------------------------------------- launch ---
extern "C" void kernel_launch(void* const* d_in, const int* in_sizes, int n_in,
                              void* d_out, int out_size, void* d_ws, size_t ws_size,
                              hipStream_t stream) {
    (void)in_sizes; (void)n_in; (void)out_size; (void)ws_size;
    const float* input_data = (const float*)d_in[0];
    const float* w1 = (const float*)d_in[2];
    const float* g1 = (const float*)d_in[3];
    const float* b1 = (const float*)d_in[4];
    const float* w2 = (const float*)d_in[5];
    const float* g2 = (const float*)d_in[6];
    const float* b2 = (const float*)d_in[7];
    const float* w3 = (const float*)d_in[8];
    const float* g3 = (const float*)d_in[9];
    const float* b3 = (const float*)d_in[10];
    const float* w4 = (const float*)d_in[11];
    const float* g4 = (const float*)d_in[12];
    const float* b4 = (const float*)d_in[13];
    const float* w5 = (const float*)d_in[14];
    const float* b5 = (const float*)d_in[15];

    char* ws = (char*)d_ws;
    float* regA = (float*)ws;               // 16.8 MB: conv1out / conv3out
    char* wsB = ws + 16777216;              // 10.7 MB: plane1 / plane2
    char* wsC = wsB + 10616832;             // 9.5 MB: rendered / conv2out / a4
    char* wsD = wsC + 9469952;
    float* h4  = (float*)wsD;                               // 262,144 B
    float* st1 = (float*)(wsD + 262144);                    // 512 B  (64*2)
    float* st2 = (float*)(wsD + 262656);                    // 1024 B (128*2)
    float* st3 = (float*)(wsD + 263680);                    // 2048 B (256*2)
    float* st4 = (float*)(wsD + 265728);                    // 8192 B (1024*2)
    unsigned short* wT1 = (unsigned short*)(wsD + 274432);  // 61,440 B
    unsigned short* wT2 = (unsigned short*)(wsD + 335872);  // 409,600 B
    unsigned short* wT3 = (unsigned short*)(wsD + 745472);  // 1,638,400 B

    unsigned short* rendered = (unsigned short*)wsC;
    float* conv1out = regA;
    unsigned short* plane1 = (unsigned short*)wsB;  // [64][2][2][2][18][18][32] = 10,616,832 B
    float* conv2out = (float*)wsC;
    unsigned short* plane2 = (unsigned short*)wsB;  // [64][2][2][4][10][10][32] = 6,553,600 B
    float* conv3out = regA;
    unsigned short* a4 = (unsigned short*)wsC;

    // one memset covers h4 + all stat accumulators
    hipMemsetAsync(wsD, 0, 273920, stream);
    wtrans_all<<<4120, 256, 0, stream>>>(w1, w2, w3, wT1, wT2, wT3);
    render_kernel<<<1024, 256, 0, stream>>>(input_data, rendered);

    // conv1: [65536,480]x[480,64] — 256 blocks x 4 waves, NT=4, CH=5 (coalesced A)
    conv_mfma<16, 64, 68, 10, 5, 3, 1, 4, 5, 4><<<256, 256, 0, stream>>>(rendered, wT1, conv1out, st1);
    // BN1 + lrelu -> parity planes for conv2 (PH=18, OCT=2): 5,308,416 elems
    bnpad_plane<<<20736, 256, 0, stream>>>(conv1out, st1, g1, b1, plane1, 6, 32, 18, 1, 1.f / 65536.f, 5308416);

    // conv2: [16384,1600]x[1600,128] — 64m x 4co = 256 blocks x 4 waves, NT=2, CH=10
    conv_plane<128, 18, 8, 4, 10, 4, 2, 10, 4, 1><<<256, 256, 0, stream>>>(plane1, wT2, conv2out, st2);
    // BN2 + lrelu -> parity planes for conv3 (PH=10, OCT=4): 3,276,800 elems
    bnpad_plane<<<12800, 256, 0, stream>>>(conv2out, st2, g2, b2, plane2, 7, 16, 10, 2, 1.f / 16384.f, 3276800);

    // conv3: [4096,3200]x[3200,256] — 32m x 8co = 256 blocks x 2 waves, NT=2, CH=10
    conv_plane<256, 10, 6, 3, 20, 8, 2, 10, 2, 2><<<256, 128, 0, stream>>>(plane2, wT3, conv3out, st3);
    bn_nchw_kernel<<<4096, 256, 0, stream>>>(conv3out, st3, g3, b3, a4, 1048576);

    // conv4: [64,16384] x [1024,16384]^T -> [64,1024], split-K=16
    conv4_mfma<<<256, 256, 0, stream>>>(a4, w4, h4);
    stats_part<<<16, 256, 0, stream>>>(h4, st4, 1024, 64, 64, 4);

    // conv5 (inline BN4)
    conv5_kernel<<<64, 256, 0, stream>>>(h4, st4, g4, b4, w5, b5, (float*)d_out);
}

// Round 11
// 250.400 us; speedup vs baseline: 1.3204x; 1.0413x over previous
//
#include <hip/hip_runtime.h>
#include <hip/hip_bf16.h>

#define NEG 0.01f
#define EPS 1e-5f

typedef __attribute__((ext_vector_type(8))) short short8;
typedef __attribute__((ext_vector_type(4))) float floatx4;

__device__ inline unsigned short f2bf(float f) {
    __hip_bfloat16 h = __float2bfloat16(f);
    union { __hip_bfloat16 h; unsigned short u; } cv; cv.h = h;
    return cv.u;
}

// ---------------------------------------------------------------- render ----
// Writes padded NHWC bf16 [64][68][68][16] INCLUDING zero borders + ch14/15.
__global__ __launch_bounds__(256) void render_kernel(const float* __restrict__ in,
                                                     unsigned short* __restrict__ out) {
    int xcd = blockIdx.x & 7, ii = blockIdx.x >> 3;
    int b = xcd * 8 + (ii >> 4);
    int chunk = ii & 15;
    __shared__ float r0[46], r1[46], r2[46], r3[46];
    __shared__ float cls_s[46 * 14];
    int tid = threadIdx.x;
    if (tid < 46) {
        const float* p = in + ((size_t)b * 46 + tid) * 18 + 14;
        float x = p[0] * 64.f, y = p[1] * 64.f, w = p[2] * 64.f, h = p[3] * 64.f;
        r0[tid] = x - 0.5f * w; r1[tid] = x + 0.5f * w;
        r2[tid] = y - 0.5f * h; r3[tid] = y + 0.5f * h;
    }
    for (int idx = tid; idx < 46 * 14; idx += 256) {
        int n = idx / 14, c = idx % 14;
        cls_s[idx] = in[((size_t)b * 46 + n) * 18 + c];
    }
    __syncthreads();
    if (tid < 33) {
        int j = chunk * 33 + tid;
        if (j < 528) {
            int y, x;
            if (j < 136) { y = j / 68; x = j - y * 68; }
            else if (j < 272) { int t = j - 136; int yy = t / 68; y = 66 + yy; x = t - yy * 68; }
            else { int t = j - 272; y = 2 + (t >> 2); int k = t & 3; x = (k < 2) ? k : 64 + k; }
            size_t zb = (((size_t)b * 68 + y) * 68 + x) * 16;
            short8 z;
#pragma unroll
            for (int i = 0; i < 8; ++i) z[i] = 0;
            *(short8*)(out + zb) = z;
            *(short8*)(out + zb + 8) = z;
        }
    }
    int pix = chunk * 256 + tid;
    float cx = (float)(pix & 63);
    float cy = (float)(pix >> 6);
    float acc[14];
#pragma unroll
    for (int c = 0; c < 14; ++c) acc[c] = 0.f;
    for (int n = 0; n < 46; ++n) {
        float x0 = r0[n], x1 = r1[n], y0 = r2[n], y1 = r3[n];
        float by = fminf(fmaxf(cy - y0, 0.f), 1.f) * fminf(fmaxf(y1 - cy, 0.f), 1.f);
        float bx = fminf(fmaxf(cx - x0, 0.f), 1.f) * fminf(fmaxf(x1 - cx, 0.f), 1.f);
        float kx0 = fmaxf(1.f - fabsf(cx - x0), 0.f);
        float kx1 = fmaxf(1.f - fabsf(cx - x1), 0.f);
        float ky0 = fmaxf(1.f - fabsf(cy - y0), 0.f);
        float ky1 = fmaxf(1.f - fabsf(cy - y1), 0.f);
        float r = fmaxf(fmaxf(kx0 * by, kx1 * by), fmaxf(ky0 * bx, ky1 * bx));
        if (r > 0.f) {
#pragma unroll
            for (int c = 0; c < 14; ++c) acc[c] = fmaf(cls_s[n * 14 + c], r, acc[c]);
        }
    }
    size_t obase = (((size_t)b * 68 + ((pix >> 6) + 2)) * 68 + ((pix & 63) + 2)) * 16;
    short8 v0, v1;
#pragma unroll
    for (int i = 0; i < 8; ++i) v0[i] = (short)f2bf(acc[i]);
#pragma unroll
    for (int i = 0; i < 6; ++i) v1[i] = (short)f2bf(acc[8 + i]);
    v1[6] = 0; v1[7] = 0;
    *(short8*)(out + obase) = v0;
    *(short8*)(out + obase + 8) = v1;
}

// ------------------------------------------- merged weight transform --------
__global__ __launch_bounds__(256) void wtrans_all(const float* __restrict__ w1,
                                                  const float* __restrict__ w2,
                                                  const float* __restrict__ w3,
                                                  unsigned short* __restrict__ wT1,
                                                  unsigned short* __restrict__ wT2,
                                                  unsigned short* __restrict__ wT3) {
    int idx = blockIdx.x * 256 + threadIdx.x;
    const float* w; unsigned short* wT; int CIN, CPLOG, SUB, COLOG;
    if (idx < 30720) { w = w1; wT = wT1; CIN = 14; CPLOG = 4; SUB = 3; COLOG = 6; }
    else if (idx < 235520) { idx -= 30720; w = w2; wT = wT2; CIN = 64; CPLOG = 6; SUB = 10; COLOG = 7; }
    else if (idx < 1054720) { idx -= 235520; w = w3; wT = wT3; CIN = 128; CPLOG = 7; SUB = 20; COLOG = 8; }
    else return;
    int kk = idx & 31;
    int co = (idx >> 5) & ((1 << COLOG) - 1);
    int s = idx >> (5 + COLOG);
    int kh = s / SUB, sub = s - kh * SUB;
    int kidx = sub * 32 + kk;
    int kw = kidx >> CPLOG;
    int ci = kidx & ((1 << CPLOG) - 1);
    float v = (kw < 5 && ci < CIN) ? w[((size_t)(co * CIN + ci) * 5 + kh) * 5 + kw] : 0.f;
    wT[idx] = f2bf(v);
}

// ------------------------------------------- implicit-GEMM MFMA conv --------
// (verified R4 kernel, unchanged; used for conv1 whose A is coalesced)
template <int CP, int COUT, int HP, int LOG_OHW, int LOG_OW, int SUB,
          int NCO, int NT, int CH, int NW>
__global__ __launch_bounds__(NW * 64) void conv_mfma(
        const unsigned short* __restrict__ inP,
        const unsigned short* __restrict__ wT,
        float* __restrict__ outX,
        float* __restrict__ stacc) {
    constexpr int NSTEP = 5 * SUB;
    constexpr int NCHUNK = NSTEP / CH;
    constexpr int COT = NT * 16;
    constexpr int NSTG = (CH * COT * 4) / (NW * 64);
    static_assert(NSTEP % CH == 0, "CH must divide NSTEP");
    __shared__ short Bs[2][CH][COT][32];
    __shared__ float sred[NW][2][COT];
    int tid = threadIdx.x;
    int wave = tid >> 6, lane = tid & 63, q = lane >> 4, l16 = lane & 15;
    int cpx = gridDim.x >> 3;
    int lb = (blockIdx.x & 7) * cpx + (blockIdx.x >> 3);
    int bm = lb / NCO, bco = lb % NCO;

    const short* aB[4];
#pragma unroll
    for (int f = 0; f < 4; ++f) {
        int m = bm * (NW * 64) + wave * 64 + f * 16 + l16;
        int b = m >> LOG_OHW;
        int ohw = m & ((1 << LOG_OHW) - 1);
        int oh = ohw >> LOG_OW, ow = ohw & ((1 << LOG_OW) - 1);
        aB[f] = (const short*)inP + ((size_t)((b * HP + 2 * oh) * HP + 2 * ow)) * CP + q * 8;
    }
    const short* bgbase = (const short*)wT + (size_t)bco * COT * 32;

    floatx4 acc[4][NT];
#pragma unroll
    for (int f = 0; f < 4; ++f)
#pragma unroll
        for (int nt = 0; nt < NT; ++nt) acc[f][nt] = (floatx4){0.f, 0.f, 0.f, 0.f};

    short8 nb[NSTG];
#pragma unroll
    for (int i = 0; i < NSTG; ++i) {
        int v = tid + i * NW * 64;
        int s = v / (COT * 4);
        int rem = v - s * (COT * 4);
        nb[i] = *(const short8*)(bgbase + ((size_t)s * COUT) * 32 + rem * 8);
    }
#pragma unroll
    for (int i = 0; i < NSTG; ++i) {
        int v = tid + i * NW * 64;
        int s = v / (COT * 4);
        int rem = v - s * (COT * 4);
        *(short8*)((short*)&Bs[0][s][0][0] + rem * 8) = nb[i];
    }
    __syncthreads();

    for (int chunk = 0; chunk < NCHUNK; ++chunk) {
        int cur = chunk & 1;
        if (chunk + 1 < NCHUNK) {
            int step0 = (chunk + 1) * CH;
#pragma unroll
            for (int i = 0; i < NSTG; ++i) {
                int v = tid + i * NW * 64;
                int s = v / (COT * 4);
                int rem = v - s * (COT * 4);
                nb[i] = *(const short8*)(bgbase + ((size_t)(step0 + s) * COUT) * 32 + rem * 8);
            }
        }
#pragma unroll
        for (int s = 0; s < CH; ++s) {
            int step = chunk * CH + s;
            int kh = step / SUB, sub = step - kh * SUB;
            short8 af[4];
#pragma unroll
            for (int f = 0; f < 4; ++f)
                af[f] = *(const short8*)(aB[f] + (size_t)(kh * HP) * CP + sub * 32);
#pragma unroll
            for (int nt = 0; nt < NT; ++nt) {
                short8 bf = *(const short8*)&Bs[cur][s][nt * 16 + l16][q * 8];
#pragma unroll
                for (int f = 0; f < 4; ++f)
                    acc[f][nt] = __builtin_amdgcn_mfma_f32_16x16x32_bf16(af[f], bf, acc[f][nt], 0, 0, 0);
            }
        }
        if (chunk + 1 < NCHUNK) {
#pragma unroll
            for (int i = 0; i < NSTG; ++i) {
                int v = tid + i * NW * 64;
                int s = v / (COT * 4);
                int rem = v - s * (COT * 4);
                *(short8*)((short*)&Bs[cur ^ 1][s][0][0] + rem * 8) = nb[i];
            }
            __syncthreads();
        }
    }
#pragma unroll
    for (int f = 0; f < 4; ++f)
#pragma unroll
        for (int nt = 0; nt < NT; ++nt)
#pragma unroll
            for (int rg = 0; rg < 4; ++rg) {
                int mg = bm * (NW * 64) + wave * 64 + f * 16 + q * 4 + rg;
                int co = bco * COT + nt * 16 + l16;
                outX[(size_t)mg * COUT + co] = acc[f][nt][rg];
            }
#pragma unroll
    for (int nt = 0; nt < NT; ++nt) {
        float s = 0.f, s2 = 0.f;
#pragma unroll
        for (int f = 0; f < 4; ++f)
#pragma unroll
            for (int rg = 0; rg < 4; ++rg) {
                float v = acc[f][nt][rg];
                s += v; s2 = fmaf(v, v, s2);
            }
        s += __shfl_xor(s, 16); s += __shfl_xor(s, 32);
        s2 += __shfl_xor(s2, 16); s2 += __shfl_xor(s2, 32);
        if (q == 0) {
            sred[wave][0][nt * 16 + l16] = s;
            sred[wave][1][nt * 16 + l16] = s2;
        }
    }
    __syncthreads();
    if (tid < COT) {
        float ts = 0.f, ts2 = 0.f;
#pragma unroll
        for (int w = 0; w < NW; ++w) { ts += sred[w][0][tid]; ts2 += sred[w][1][tid]; }
        atomicAdd(&stacc[bco * COT + tid], ts);
        atomicAdd(&stacc[COUT + bco * COT + tid], ts2);
    }
}

// --------------------- conv on parity-plane A layout (conv2, conv3) ---------
// (verified R10 kernel, unchanged)
template <int COUT, int PH, int LOG_OHW, int LOG_OW, int SUB,
          int NCO, int NT, int CH, int NW, int KWSH>
__global__ __launch_bounds__(NW * 64) void conv_plane(
        const unsigned short* __restrict__ inP,
        const unsigned short* __restrict__ wT,
        float* __restrict__ outX,
        float* __restrict__ stacc) {
    constexpr int OCT = 1 << KWSH;
    constexpr int NSTEP = 5 * SUB;
    constexpr int NCHUNK = NSTEP / CH;
    constexpr int COT = NT * 16;
    constexpr int NSTG = (CH * COT * 4) / (NW * 64);
    constexpr int PPS = PH * PH * 32;
    static_assert(NSTEP % CH == 0, "CH must divide NSTEP");
    __shared__ short Bs[2][CH][COT][32];
    __shared__ float sred[NW][2][COT];
    int tid = threadIdx.x;
    int wave = tid >> 6, lane = tid & 63, q = lane >> 4, l16 = lane & 15;
    int cpx = gridDim.x >> 3;
    int lb = (blockIdx.x & 7) * cpx + (blockIdx.x >> 3);
    int bm = lb / NCO, bco = lb % NCO;

    const short* aP[4];
#pragma unroll
    for (int f = 0; f < 4; ++f) {
        int m = bm * (NW * 64) + wave * 64 + f * 16 + l16;
        int b = m >> LOG_OHW;
        int ohw = m & ((1 << LOG_OHW) - 1);
        int oh = ohw >> LOG_OW, ow = ohw & ((1 << LOG_OW) - 1);
        aP[f] = (const short*)inP + (size_t)b * (4 * OCT * PPS) + (oh * PH + ow) * 32 + q * 8;
    }
    const short* bgbase = (const short*)wT + (size_t)bco * COT * 32;

    floatx4 acc[4][NT];
#pragma unroll
    for (int f = 0; f < 4; ++f)
#pragma unroll
        for (int nt = 0; nt < NT; ++nt) acc[f][nt] = (floatx4){0.f, 0.f, 0.f, 0.f};

    short8 nb[NSTG];
#pragma unroll
    for (int i = 0; i < NSTG; ++i) {
        int v = tid + i * NW * 64;
        int s = v / (COT * 4);
        int rem = v - s * (COT * 4);
        nb[i] = *(const short8*)(bgbase + ((size_t)s * COUT) * 32 + rem * 8);
    }
#pragma unroll
    for (int i = 0; i < NSTG; ++i) {
        int v = tid + i * NW * 64;
        int s = v / (COT * 4);
        int rem = v - s * (COT * 4);
        *(short8*)((short*)&Bs[0][s][0][0] + rem * 8) = nb[i];
    }
    __syncthreads();

    for (int chunk = 0; chunk < NCHUNK; ++chunk) {
        int cur = chunk & 1;
        if (chunk + 1 < NCHUNK) {
            int step0 = (chunk + 1) * CH;
#pragma unroll
            for (int i = 0; i < NSTG; ++i) {
                int v = tid + i * NW * 64;
                int s = v / (COT * 4);
                int rem = v - s * (COT * 4);
                nb[i] = *(const short8*)(bgbase + ((size_t)(step0 + s) * COUT) * 32 + rem * 8);
            }
        }
#pragma unroll
        for (int s = 0; s < CH; ++s) {
            int step = chunk * CH + s;
            int kh = step / SUB, sub = step - kh * SUB;
            int kw = sub >> KWSH, oct = sub & (OCT - 1);
            int soff = ((((kh & 1) * 2 + (kw & 1)) * OCT + oct) * PH * PH
                        + (kh >> 1) * PH + (kw >> 1)) * 32;
            short8 af[4];
#pragma unroll
            for (int f = 0; f < 4; ++f)
                af[f] = *(const short8*)(aP[f] + soff);
#pragma unroll
            for (int nt = 0; nt < NT; ++nt) {
                short8 bf = *(const short8*)&Bs[cur][s][nt * 16 + l16][q * 8];
#pragma unroll
                for (int f = 0; f < 4; ++f)
                    acc[f][nt] = __builtin_amdgcn_mfma_f32_16x16x32_bf16(af[f], bf, acc[f][nt], 0, 0, 0);
            }
        }
        if (chunk + 1 < NCHUNK) {
#pragma unroll
            for (int i = 0; i < NSTG; ++i) {
                int v = tid + i * NW * 64;
                int s = v / (COT * 4);
                int rem = v - s * (COT * 4);
                *(short8*)((short*)&Bs[cur ^ 1][s][0][0] + rem * 8) = nb[i];
            }
            __syncthreads();
        }
    }
#pragma unroll
    for (int f = 0; f < 4; ++f)
#pragma unroll
        for (int nt = 0; nt < NT; ++nt)
#pragma unroll
            for (int rg = 0; rg < 4; ++rg) {
                int mg = bm * (NW * 64) + wave * 64 + f * 16 + q * 4 + rg;
                int co = bco * COT + nt * 16 + l16;
                outX[(size_t)mg * COUT + co] = acc[f][nt][rg];
            }
#pragma unroll
    for (int nt = 0; nt < NT; ++nt) {
        float s = 0.f, s2 = 0.f;
#pragma unroll
        for (int f = 0; f < 4; ++f)
#pragma unroll
            for (int rg = 0; rg < 4; ++rg) {
                float v = acc[f][nt][rg];
                s += v; s2 = fmaf(v, v, s2);
            }
        s += __shfl_xor(s, 16); s += __shfl_xor(s, 32);
        s2 += __shfl_xor(s2, 16); s2 += __shfl_xor(s2, 32);
        if (q == 0) {
            sred[wave][0][nt * 16 + l16] = s;
            sred[wave][1][nt * 16 + l16] = s2;
        }
    }
    __syncthreads();
    if (tid < COT) {
        float ts = 0.f, ts2 = 0.f;
#pragma unroll
        for (int w = 0; w < NW; ++w) { ts += sred[w][0][tid]; ts2 += sred[w][1][tid]; }
        atomicAdd(&stacc[bco * COT + tid], ts);
        atomicAdd(&stacc[COUT + bco * COT + tid], ts2);
    }
}

// --------------------------------------------------- conv4 split-K GEMM -----
__global__ __launch_bounds__(256) void conv4_mfma(const unsigned short* __restrict__ A,
                                                  const float* __restrict__ w4,
                                                  float* __restrict__ h4) {
    constexpr int CH = 4, NCHUNK = 8;
    __shared__ short Bs[CH][64][40];
    int tid = threadIdx.x;
    int bco = blockIdx.x & 15;
    int ks = blockIdx.x >> 4;
    int wave = tid >> 6, lane = tid & 63, q = lane >> 4, l16 = lane & 15;
    const short* aBase = (const short*)A + (size_t)(wave * 16 + l16) * 16384 + ks * 1024 + q * 8;
    int r = tid >> 2, cc = tid & 3;
    const float* bg = w4 + (size_t)(bco * 64 + r) * 16384 + ks * 1024 + cc * 8;

    floatx4 acc[4];
#pragma unroll
    for (int nt = 0; nt < 4; ++nt) acc[nt] = (floatx4){0.f, 0.f, 0.f, 0.f};

    short8 nb[CH];
#pragma unroll
    for (int s = 0; s < CH; ++s) {
        float4 b0 = *(const float4*)(bg + s * 32);
        float4 b1 = *(const float4*)(bg + s * 32 + 4);
        nb[s][0] = (short)f2bf(b0.x); nb[s][1] = (short)f2bf(b0.y);
        nb[s][2] = (short)f2bf(b0.z); nb[s][3] = (short)f2bf(b0.w);
        nb[s][4] = (short)f2bf(b1.x); nb[s][5] = (short)f2bf(b1.y);
        nb[s][6] = (short)f2bf(b1.z); nb[s][7] = (short)f2bf(b1.w);
    }
#pragma unroll
    for (int s = 0; s < CH; ++s) *(short8*)&Bs[s][r][cc * 8] = nb[s];
    __syncthreads();

    for (int chunk = 0; chunk < NCHUNK; ++chunk) {
        bool has_next = (chunk + 1 < NCHUNK);
        if (has_next) {
#pragma unroll
            for (int s = 0; s < CH; ++s) {
                int step = (chunk + 1) * CH + s;
                float4 b0 = *(const float4*)(bg + step * 32);
                float4 b1 = *(const float4*)(bg + step * 32 + 4);
                nb[s][0] = (short)f2bf(b0.x); nb[s][1] = (short)f2bf(b0.y);
                nb[s][2] = (short)f2bf(b0.z); nb[s][3] = (short)f2bf(b0.w);
                nb[s][4] = (short)f2bf(b1.x); nb[s][5] = (short)f2bf(b1.y);
                nb[s][6] = (short)f2bf(b1.z); nb[s][7] = (short)f2bf(b1.w);
            }
        }
#pragma unroll
        for (int s = 0; s < CH; ++s) {
            int step = chunk * CH + s;
            short8 af = *(const short8*)(aBase + step * 32);
#pragma unroll
            for (int nt = 0; nt < 4; ++nt) {
                short8 bf = *(const short8*)&Bs[s][nt * 16 + l16][q * 8];
                acc[nt] = __builtin_amdgcn_mfma_f32_16x16x32_bf16(af, bf, acc[nt], 0, 0, 0);
            }
        }
        if (has_next) {
            __syncthreads();
#pragma unroll
            for (int s = 0; s < CH; ++s) *(short8*)&Bs[s][r][cc * 8] = nb[s];
            __syncthreads();
        }
    }
#pragma unroll
    for (int nt = 0; nt < 4; ++nt) {
#pragma unroll
        for (int rg = 0; rg < 4; ++rg) {
            int mg = wave * 16 + q * 4 + rg;
            int co = bco * 64 + nt * 16 + l16;
            atomicAdd(&h4[(size_t)mg * 1024 + co], acc[nt][rg]);
        }
    }
}

// ----------------------------------------------------------- batch stats ----
__global__ __launch_bounds__(256) void stats_part(const float* __restrict__ X,
                                                  float* __restrict__ acc,
                                                  int CO, int R, int RPB, int CGLOG) {
    int tid = threadIdx.x;
    int cg = blockIdx.x & ((1 << CGLOG) - 1);
    int rb = blockIdx.x >> CGLOG;
    int c = (cg << 6) + (tid & 63);
    int w = tid >> 6;
    float s = 0.f, s2 = 0.f;
    int rend = min(R, (rb + 1) * RPB);
    for (int r = rb * RPB + w; r < rend; r += 4) {
        float v = X[(size_t)r * CO + c];
        s += v; s2 += v * v;
    }
    __shared__ float ls[4][64], ls2[4][64];
    ls[w][tid & 63] = s; ls2[w][tid & 63] = s2;
    __syncthreads();
    if (tid < 64) {
        float ts = ls[0][tid] + ls[1][tid] + ls[2][tid] + ls[3][tid];
        float ts2 = ls2[0][tid] + ls2[1][tid] + ls2[2][tid] + ls2[3][tid];
        int cc = (cg << 6) + tid;
        atomicAdd(&acc[cc], ts);
        atomicAdd(&acc[CO + cc], ts2);
    }
}

// ---- BN(inline finalize) + lrelu + bf16 -> parity-plane layout, 8-wide -----
// Thread = 8 consecutive channels: 2x float4 read (one fully-used 128B line)
// + 1x short8 store (wave = 1KB contiguous). Same per-element arithmetic as
// the scalar version (bit-identical). Grid = total/8/256, XCD swizzle kept.
__global__ __launch_bounds__(256) void bnpad_plane8(const float* __restrict__ X,
                                                    const float* __restrict__ stacc,
                                                    const float* __restrict__ g,
                                                    const float* __restrict__ bb,
                                                    unsigned short* __restrict__ out,
                                                    int CO_LOG, int OH, int PH,
                                                    int OCTLOG, float invN, int vtotal) {
    int nb8 = gridDim.x >> 3;
    int sb = (blockIdx.x & 7) * nb8 + (blockIdx.x >> 3);
    int vidx = sb * 256 + threadIdx.x;
    if (vidx >= vtotal) return;
    int CO = 1 << CO_LOG;
    int c8 = (vidx & 3) << 3;
    int t = vidx >> 2;
    int xp = t % PH; t /= PH;
    int yp = t % PH; t /= PH;
    int oct = t & ((1 << OCTLOG) - 1); t >>= OCTLOG;
    int px = t & 1, py = (t >> 1) & 1;
    int b = t >> 2;
    int cbase = (oct << 5) + c8;
    int y = 2 * yp + py - 2, x = 2 * xp + px - 2;
    short8 v;
    if ((unsigned)y < (unsigned)OH && (unsigned)x < (unsigned)OH) {
        const float* p = X + (((size_t)(b * OH + y) * OH + x)) * CO + cbase;
        float4 lo = *(const float4*)p;
        float4 hi = *(const float4*)(p + 4);
        float lv[8] = {lo.x, lo.y, lo.z, lo.w, hi.x, hi.y, hi.z, hi.w};
#pragma unroll
        for (int j = 0; j < 8; ++j) {
            int c = cbase + j;
            float mean = stacc[c] * invN;
            float var = fmaxf(stacc[CO + c] * invN - mean * mean, 0.f);
            float sc = g[c] * rsqrtf(var + EPS);
            float sh = bb[c] - mean * sc;
            float f = lv[j] * sc + sh;
            f = f >= 0.f ? f : NEG * f;
            v[j] = (short)f2bf(f);
        }
    } else {
#pragma unroll
        for (int j = 0; j < 8; ++j) v[j] = 0;
    }
    *(short8*)(out + (size_t)vidx * 8) = v;
}

// -- BN(inline finalize) + lrelu + bf16, NHWC -> NCHW, 8-wide (conv4 input) --
// Thread = 8 consecutive hw for one ci: BN coeffs computed ONCE per thread
// (was 8x); short8 store (wave = 1KB contiguous); reads pull full 128B lines
// through L1 (block covers a 32-ci x 64-hw slab -> every fetched line fully
// consumed). vtotal = 131072.
__global__ __launch_bounds__(256) void bn_nchw8(const float* __restrict__ X,
                                                const float* __restrict__ stacc,
                                                const float* __restrict__ g,
                                                const float* __restrict__ bb,
                                                unsigned short* __restrict__ out,
                                                int vtotal) {
    int nb8 = gridDim.x >> 3;
    int sb = (blockIdx.x & 7) * nb8 + (blockIdx.x >> 3);
    int vidx = sb * 256 + threadIdx.x;
    if (vidx >= vtotal) return;
    int hw8 = (vidx & 7) << 3;
    int ci = (vidx >> 3) & 255;
    int b = vidx >> 11;
    float mean = stacc[ci] * (1.f / 4096.f);
    float var = fmaxf(stacc[256 + ci] * (1.f / 4096.f) - mean * mean, 0.f);
    float sc = g[ci] * rsqrtf(var + EPS);
    float sh = bb[ci] - mean * sc;
    short8 v;
#pragma unroll
    for (int j = 0; j < 8; ++j) {
        float f = X[((size_t)(b * 64 + hw8 + j)) * 256 + ci] * sc + sh;
        f = f >= 0.f ? f : NEG * f;
        v[j] = (short)f2bf(f);
    }
    *(short8*)(out + (size_t)vidx * 8) = v;
}

// -------------------------------------- conv5 (inline BN4 finalize) ---------
__global__ __launch_bounds__(256) void conv5_kernel(const float* __restrict__ X,
                                                    const float* __restrict__ stacc,
                                                    const float* __restrict__ g,
                                                    const float* __restrict__ bb,
                                                    const float* __restrict__ w5,
                                                    const float* __restrict__ b5,
                                                    float* __restrict__ out) {
    int b = blockIdx.x, tid = threadIdx.x;
    float s = 0.f;
    for (int c = tid; c < 1024; c += 256) {
        float mean = stacc[c] * (1.f / 64.f);
        float var = fmaxf(stacc[1024 + c] * (1.f / 64.f) - mean * mean, 0.f);
        float sc = g[c] * rsqrtf(var + EPS);
        float sh = bb[c] - mean * sc;
        float f = X[(size_t)b * 1024 + c] * sc + sh;
        f = f >= 0.f ? f : NEG * f;
        s = fmaf(f, w5[c], s);
    }
#pragma unroll
    for (int off = 32; off > 0; off >>= 1) s += __shfl_down(s, off);
    __shared__ float ls[4];
    if ((tid & 63) == 0) ls[tid >> 6] = s;
    __syncthreads();
    if (tid == 0) out[b] = ls[0] + ls[1] + ls[2] + ls[3] + b5[0];
}

// ----------------------------------------------------------------- launch ---
extern "C" void kernel_launch(void* const* d_in, const int* in_sizes, int n_in,
                              void* d_out, int out_size, void* d_ws, size_t ws_size,
                              hipStream_t stream) {
    (void)in_sizes; (void)n_in; (void)out_size; (void)ws_size;
    const float* input_data = (const float*)d_in[0];
    const float* w1 = (const float*)d_in[2];
    const float* g1 = (const float*)d_in[3];
    const float* b1 = (const float*)d_in[4];
    const float* w2 = (const float*)d_in[5];
    const float* g2 = (const float*)d_in[6];
    const float* b2 = (const float*)d_in[7];
    const float* w3 = (const float*)d_in[8];
    const float* g3 = (const float*)d_in[9];
    const float* b3 = (const float*)d_in[10];
    const float* w4 = (const float*)d_in[11];
    const float* g4 = (const float*)d_in[12];
    const float* b4 = (const float*)d_in[13];
    const float* w5 = (const float*)d_in[14];
    const float* b5 = (const float*)d_in[15];

    char* ws = (char*)d_ws;
    float* regA = (float*)ws;               // 16.8 MB: conv1out / conv3out
    char* wsB = ws + 16777216;              // 10.7 MB: plane1 / plane2
    char* wsC = wsB + 10616832;             // 9.5 MB: rendered / conv2out / a4
    char* wsD = wsC + 9469952;
    float* h4  = (float*)wsD;                               // 262,144 B
    float* st1 = (float*)(wsD + 262144);                    // 512 B  (64*2)
    float* st2 = (float*)(wsD + 262656);                    // 1024 B (128*2)
    float* st3 = (float*)(wsD + 263680);                    // 2048 B (256*2)
    float* st4 = (float*)(wsD + 265728);                    // 8192 B (1024*2)
    unsigned short* wT1 = (unsigned short*)(wsD + 274432);  // 61,440 B
    unsigned short* wT2 = (unsigned short*)(wsD + 335872);  // 409,600 B
    unsigned short* wT3 = (unsigned short*)(wsD + 745472);  // 1,638,400 B

    unsigned short* rendered = (unsigned short*)wsC;
    float* conv1out = regA;
    unsigned short* plane1 = (unsigned short*)wsB;  // [64][2][2][2][18][18][32] = 10,616,832 B
    float* conv2out = (float*)wsC;
    unsigned short* plane2 = (unsigned short*)wsB;  // [64][2][2][4][10][10][32] = 6,553,600 B
    float* conv3out = regA;
    unsigned short* a4 = (unsigned short*)wsC;

    // one memset covers h4 + all stat accumulators
    hipMemsetAsync(wsD, 0, 273920, stream);
    wtrans_all<<<4120, 256, 0, stream>>>(w1, w2, w3, wT1, wT2, wT3);
    render_kernel<<<1024, 256, 0, stream>>>(input_data, rendered);

    // conv1: [65536,480]x[480,64] — 256 blocks x 4 waves, NT=4, CH=5 (coalesced A)
    conv_mfma<16, 64, 68, 10, 5, 3, 1, 4, 5, 4><<<256, 256, 0, stream>>>(rendered, wT1, conv1out, st1);
    // BN1 + lrelu -> parity planes for conv2 (PH=18, OCT=2): 663,552 vec8 elems
    bnpad_plane8<<<2592, 256, 0, stream>>>(conv1out, st1, g1, b1, plane1, 6, 32, 18, 1, 1.f / 65536.f, 663552);

    // conv2: [16384,1600]x[1600,128] — 64m x 4co = 256 blocks x 4 waves, NT=2, CH=10
    conv_plane<128, 18, 8, 4, 10, 4, 2, 10, 4, 1><<<256, 256, 0, stream>>>(plane1, wT2, conv2out, st2);
    // BN2 + lrelu -> parity planes for conv3 (PH=10, OCT=4): 409,600 vec8 elems
    bnpad_plane8<<<1600, 256, 0, stream>>>(conv2out, st2, g2, b2, plane2, 7, 16, 10, 2, 1.f / 16384.f, 409600);

    // conv3: [4096,3200]x[3200,256] — 32m x 8co = 256 blocks x 2 waves, NT=2, CH=10
    conv_plane<256, 10, 6, 3, 20, 8, 2, 10, 2, 2><<<256, 128, 0, stream>>>(plane2, wT3, conv3out, st3);
    bn_nchw8<<<512, 256, 0, stream>>>(conv3out, st3, g3, b3, a4, 131072);

    // conv4: [64,16384] x [1024,16384]^T -> [64,1024], split-K=16
    conv4_mfma<<<256, 256, 0, stream>>>(a4, w4, h4);
    stats_part<<<16, 256, 0, stream>>>(h4, st4, 1024, 64, 64, 4);

    // conv5 (inline BN4)
    conv5_kernel<<<64, 256, 0, stream>>>(h4, st4, g4, b4, w5, b5, (float*)d_out);
}

// Round 12
// 241.618 us; speedup vs baseline: 1.3684x; 1.0364x over previous
//
#include <hip/hip_runtime.h>
#include <hip/hip_bf16.h>

#define NEG 0.01f
#define EPS 1e-5f

typedef __attribute__((ext_vector_type(8))) short short8;
typedef __attribute__((ext_vector_type(4))) float floatx4;

__device__ inline unsigned short f2bf(float f) {
    __hip_bfloat16 h = __float2bfloat16(f);
    union { __hip_bfloat16 h; unsigned short u; } cv; cv.h = h;
    return cv.u;
}

// ---------------- head: render + weight transform + ws zeroing (fused) ------
// blocks [0,1024):        render (XCD-aligned batches)
// blocks [1024,5144):     weight transform (1,054,720 threads)
// blocks [5144,5211):     zero the 273,920-byte stats/h4 region (float4 x 17,120)
__global__ __launch_bounds__(256) void head_kernel(const float* __restrict__ in,
                                                   unsigned short* __restrict__ out,
                                                   const float* __restrict__ w1,
                                                   const float* __restrict__ w2,
                                                   const float* __restrict__ w3,
                                                   unsigned short* __restrict__ wT1,
                                                   unsigned short* __restrict__ wT2,
                                                   unsigned short* __restrict__ wT3,
                                                   float* __restrict__ zbase) {
    __shared__ float r0[46], r1[46], r2[46], r3[46];
    __shared__ float cls_s[46 * 14];
    int tid = threadIdx.x;
    if (blockIdx.x >= 5144) {
        int idx = (blockIdx.x - 5144) * 256 + tid;
        if (idx < 17120) {
            floatx4 z = (floatx4){0.f, 0.f, 0.f, 0.f};
            *(floatx4*)(zbase + (size_t)idx * 4) = z;
        }
        return;
    }
    if (blockIdx.x >= 1024) {
        int idx = (blockIdx.x - 1024) * 256 + tid;
        const float* w; unsigned short* wT; int CIN, CPLOG, SUB, COLOG;
        if (idx < 30720) { w = w1; wT = wT1; CIN = 14; CPLOG = 4; SUB = 3; COLOG = 6; }
        else if (idx < 235520) { idx -= 30720; w = w2; wT = wT2; CIN = 64; CPLOG = 6; SUB = 10; COLOG = 7; }
        else if (idx < 1054720) { idx -= 235520; w = w3; wT = wT3; CIN = 128; CPLOG = 7; SUB = 20; COLOG = 8; }
        else return;
        int kk = idx & 31;
        int co = (idx >> 5) & ((1 << COLOG) - 1);
        int s = idx >> (5 + COLOG);
        int kh = s / SUB, sub = s - kh * SUB;
        int kidx = sub * 32 + kk;
        int kw = kidx >> CPLOG;
        int ci = kidx & ((1 << CPLOG) - 1);
        float v = (kw < 5 && ci < CIN) ? w[((size_t)(co * CIN + ci) * 5 + kh) * 5 + kw] : 0.f;
        wT[idx] = f2bf(v);
        return;
    }
    int xcd = blockIdx.x & 7, ii = blockIdx.x >> 3;
    int b = xcd * 8 + (ii >> 4);
    int chunk = ii & 15;
    if (tid < 46) {
        const float* p = in + ((size_t)b * 46 + tid) * 18 + 14;
        float x = p[0] * 64.f, y = p[1] * 64.f, w = p[2] * 64.f, h = p[3] * 64.f;
        r0[tid] = x - 0.5f * w; r1[tid] = x + 0.5f * w;
        r2[tid] = y - 0.5f * h; r3[tid] = y + 0.5f * h;
    }
    for (int idx = tid; idx < 46 * 14; idx += 256) {
        int n = idx / 14, c = idx % 14;
        cls_s[idx] = in[((size_t)b * 46 + n) * 18 + c];
    }
    __syncthreads();
    if (tid < 33) {
        int j = chunk * 33 + tid;
        if (j < 528) {
            int y, x;
            if (j < 136) { y = j / 68; x = j - y * 68; }
            else if (j < 272) { int t = j - 136; int yy = t / 68; y = 66 + yy; x = t - yy * 68; }
            else { int t = j - 272; y = 2 + (t >> 2); int k = t & 3; x = (k < 2) ? k : 64 + k; }
            size_t zb = (((size_t)b * 68 + y) * 68 + x) * 16;
            short8 z;
#pragma unroll
            for (int i = 0; i < 8; ++i) z[i] = 0;
            *(short8*)(out + zb) = z;
            *(short8*)(out + zb + 8) = z;
        }
    }
    int pix = chunk * 256 + tid;
    float cx = (float)(pix & 63);
    float cy = (float)(pix >> 6);
    float acc[14];
#pragma unroll
    for (int c = 0; c < 14; ++c) acc[c] = 0.f;
    for (int n = 0; n < 46; ++n) {
        float x0 = r0[n], x1 = r1[n], y0 = r2[n], y1 = r3[n];
        float by = fminf(fmaxf(cy - y0, 0.f), 1.f) * fminf(fmaxf(y1 - cy, 0.f), 1.f);
        float bx = fminf(fmaxf(cx - x0, 0.f), 1.f) * fminf(fmaxf(x1 - cx, 0.f), 1.f);
        float kx0 = fmaxf(1.f - fabsf(cx - x0), 0.f);
        float kx1 = fmaxf(1.f - fabsf(cx - x1), 0.f);
        float ky0 = fmaxf(1.f - fabsf(cy - y0), 0.f);
        float ky1 = fmaxf(1.f - fabsf(cy - y1), 0.f);
        float r = fmaxf(fmaxf(kx0 * by, kx1 * by), fmaxf(ky0 * bx, ky1 * bx));
        if (r > 0.f) {
#pragma unroll
            for (int c = 0; c < 14; ++c) acc[c] = fmaf(cls_s[n * 14 + c], r, acc[c]);
        }
    }
    size_t obase = (((size_t)b * 68 + ((pix >> 6) + 2)) * 68 + ((pix & 63) + 2)) * 16;
    short8 v0, v1;
#pragma unroll
    for (int i = 0; i < 8; ++i) v0[i] = (short)f2bf(acc[i]);
#pragma unroll
    for (int i = 0; i < 6; ++i) v1[i] = (short)f2bf(acc[8 + i]);
    v1[6] = 0; v1[7] = 0;
    *(short8*)(out + obase) = v0;
    *(short8*)(out + obase + 8) = v1;
}

// ------------------------------------------- implicit-GEMM MFMA conv --------
// (verified R4 kernel, unchanged; used for conv1 whose A is coalesced)
template <int CP, int COUT, int HP, int LOG_OHW, int LOG_OW, int SUB,
          int NCO, int NT, int CH, int NW>
__global__ __launch_bounds__(NW * 64) void conv_mfma(
        const unsigned short* __restrict__ inP,
        const unsigned short* __restrict__ wT,
        float* __restrict__ outX,
        float* __restrict__ stacc) {
    constexpr int NSTEP = 5 * SUB;
    constexpr int NCHUNK = NSTEP / CH;
    constexpr int COT = NT * 16;
    constexpr int NSTG = (CH * COT * 4) / (NW * 64);
    static_assert(NSTEP % CH == 0, "CH must divide NSTEP");
    __shared__ short Bs[2][CH][COT][32];
    __shared__ float sred[NW][2][COT];
    int tid = threadIdx.x;
    int wave = tid >> 6, lane = tid & 63, q = lane >> 4, l16 = lane & 15;
    int cpx = gridDim.x >> 3;
    int lb = (blockIdx.x & 7) * cpx + (blockIdx.x >> 3);
    int bm = lb / NCO, bco = lb % NCO;

    const short* aB[4];
#pragma unroll
    for (int f = 0; f < 4; ++f) {
        int m = bm * (NW * 64) + wave * 64 + f * 16 + l16;
        int b = m >> LOG_OHW;
        int ohw = m & ((1 << LOG_OHW) - 1);
        int oh = ohw >> LOG_OW, ow = ohw & ((1 << LOG_OW) - 1);
        aB[f] = (const short*)inP + ((size_t)((b * HP + 2 * oh) * HP + 2 * ow)) * CP + q * 8;
    }
    const short* bgbase = (const short*)wT + (size_t)bco * COT * 32;

    floatx4 acc[4][NT];
#pragma unroll
    for (int f = 0; f < 4; ++f)
#pragma unroll
        for (int nt = 0; nt < NT; ++nt) acc[f][nt] = (floatx4){0.f, 0.f, 0.f, 0.f};

    short8 nb[NSTG];
#pragma unroll
    for (int i = 0; i < NSTG; ++i) {
        int v = tid + i * NW * 64;
        int s = v / (COT * 4);
        int rem = v - s * (COT * 4);
        nb[i] = *(const short8*)(bgbase + ((size_t)s * COUT) * 32 + rem * 8);
    }
#pragma unroll
    for (int i = 0; i < NSTG; ++i) {
        int v = tid + i * NW * 64;
        int s = v / (COT * 4);
        int rem = v - s * (COT * 4);
        *(short8*)((short*)&Bs[0][s][0][0] + rem * 8) = nb[i];
    }
    __syncthreads();

    for (int chunk = 0; chunk < NCHUNK; ++chunk) {
        int cur = chunk & 1;
        if (chunk + 1 < NCHUNK) {
            int step0 = (chunk + 1) * CH;
#pragma unroll
            for (int i = 0; i < NSTG; ++i) {
                int v = tid + i * NW * 64;
                int s = v / (COT * 4);
                int rem = v - s * (COT * 4);
                nb[i] = *(const short8*)(bgbase + ((size_t)(step0 + s) * COUT) * 32 + rem * 8);
            }
        }
#pragma unroll
        for (int s = 0; s < CH; ++s) {
            int step = chunk * CH + s;
            int kh = step / SUB, sub = step - kh * SUB;
            short8 af[4];
#pragma unroll
            for (int f = 0; f < 4; ++f)
                af[f] = *(const short8*)(aB[f] + (size_t)(kh * HP) * CP + sub * 32);
#pragma unroll
            for (int nt = 0; nt < NT; ++nt) {
                short8 bf = *(const short8*)&Bs[cur][s][nt * 16 + l16][q * 8];
#pragma unroll
                for (int f = 0; f < 4; ++f)
                    acc[f][nt] = __builtin_amdgcn_mfma_f32_16x16x32_bf16(af[f], bf, acc[f][nt], 0, 0, 0);
            }
        }
        if (chunk + 1 < NCHUNK) {
#pragma unroll
            for (int i = 0; i < NSTG; ++i) {
                int v = tid + i * NW * 64;
                int s = v / (COT * 4);
                int rem = v - s * (COT * 4);
                *(short8*)((short*)&Bs[cur ^ 1][s][0][0] + rem * 8) = nb[i];
            }
            __syncthreads();
        }
    }
#pragma unroll
    for (int f = 0; f < 4; ++f)
#pragma unroll
        for (int nt = 0; nt < NT; ++nt)
#pragma unroll
            for (int rg = 0; rg < 4; ++rg) {
                int mg = bm * (NW * 64) + wave * 64 + f * 16 + q * 4 + rg;
                int co = bco * COT + nt * 16 + l16;
                outX[(size_t)mg * COUT + co] = acc[f][nt][rg];
            }
#pragma unroll
    for (int nt = 0; nt < NT; ++nt) {
        float s = 0.f, s2 = 0.f;
#pragma unroll
        for (int f = 0; f < 4; ++f)
#pragma unroll
            for (int rg = 0; rg < 4; ++rg) {
                float v = acc[f][nt][rg];
                s += v; s2 = fmaf(v, v, s2);
            }
        s += __shfl_xor(s, 16); s += __shfl_xor(s, 32);
        s2 += __shfl_xor(s2, 16); s2 += __shfl_xor(s2, 32);
        if (q == 0) {
            sred[wave][0][nt * 16 + l16] = s;
            sred[wave][1][nt * 16 + l16] = s2;
        }
    }
    __syncthreads();
    if (tid < COT) {
        float ts = 0.f, ts2 = 0.f;
#pragma unroll
        for (int w = 0; w < NW; ++w) { ts += sred[w][0][tid]; ts2 += sred[w][1][tid]; }
        atomicAdd(&stacc[bco * COT + tid], ts);
        atomicAdd(&stacc[COUT + bco * COT + tid], ts2);
    }
}

// --------------------- conv on parity-plane A layout (conv2, conv3) ---------
// (verified R10 kernel, unchanged)
template <int COUT, int PH, int LOG_OHW, int LOG_OW, int SUB,
          int NCO, int NT, int CH, int NW, int KWSH>
__global__ __launch_bounds__(NW * 64) void conv_plane(
        const unsigned short* __restrict__ inP,
        const unsigned short* __restrict__ wT,
        float* __restrict__ outX,
        float* __restrict__ stacc) {
    constexpr int OCT = 1 << KWSH;
    constexpr int NSTEP = 5 * SUB;
    constexpr int NCHUNK = NSTEP / CH;
    constexpr int COT = NT * 16;
    constexpr int NSTG = (CH * COT * 4) / (NW * 64);
    constexpr int PPS = PH * PH * 32;
    static_assert(NSTEP % CH == 0, "CH must divide NSTEP");
    __shared__ short Bs[2][CH][COT][32];
    __shared__ float sred[NW][2][COT];
    int tid = threadIdx.x;
    int wave = tid >> 6, lane = tid & 63, q = lane >> 4, l16 = lane & 15;
    int cpx = gridDim.x >> 3;
    int lb = (blockIdx.x & 7) * cpx + (blockIdx.x >> 3);
    int bm = lb / NCO, bco = lb % NCO;

    const short* aP[4];
#pragma unroll
    for (int f = 0; f < 4; ++f) {
        int m = bm * (NW * 64) + wave * 64 + f * 16 + l16;
        int b = m >> LOG_OHW;
        int ohw = m & ((1 << LOG_OHW) - 1);
        int oh = ohw >> LOG_OW, ow = ohw & ((1 << LOG_OW) - 1);
        aP[f] = (const short*)inP + (size_t)b * (4 * OCT * PPS) + (oh * PH + ow) * 32 + q * 8;
    }
    const short* bgbase = (const short*)wT + (size_t)bco * COT * 32;

    floatx4 acc[4][NT];
#pragma unroll
    for (int f = 0; f < 4; ++f)
#pragma unroll
        for (int nt = 0; nt < NT; ++nt) acc[f][nt] = (floatx4){0.f, 0.f, 0.f, 0.f};

    short8 nb[NSTG];
#pragma unroll
    for (int i = 0; i < NSTG; ++i) {
        int v = tid + i * NW * 64;
        int s = v / (COT * 4);
        int rem = v - s * (COT * 4);
        nb[i] = *(const short8*)(bgbase + ((size_t)s * COUT) * 32 + rem * 8);
    }
#pragma unroll
    for (int i = 0; i < NSTG; ++i) {
        int v = tid + i * NW * 64;
        int s = v / (COT * 4);
        int rem = v - s * (COT * 4);
        *(short8*)((short*)&Bs[0][s][0][0] + rem * 8) = nb[i];
    }
    __syncthreads();

    for (int chunk = 0; chunk < NCHUNK; ++chunk) {
        int cur = chunk & 1;
        if (chunk + 1 < NCHUNK) {
            int step0 = (chunk + 1) * CH;
#pragma unroll
            for (int i = 0; i < NSTG; ++i) {
                int v = tid + i * NW * 64;
                int s = v / (COT * 4);
                int rem = v - s * (COT * 4);
                nb[i] = *(const short8*)(bgbase + ((size_t)(step0 + s) * COUT) * 32 + rem * 8);
            }
        }
#pragma unroll
        for (int s = 0; s < CH; ++s) {
            int step = chunk * CH + s;
            int kh = step / SUB, sub = step - kh * SUB;
            int kw = sub >> KWSH, oct = sub & (OCT - 1);
            int soff = ((((kh & 1) * 2 + (kw & 1)) * OCT + oct) * PH * PH
                        + (kh >> 1) * PH + (kw >> 1)) * 32;
            short8 af[4];
#pragma unroll
            for (int f = 0; f < 4; ++f)
                af[f] = *(const short8*)(aP[f] + soff);
#pragma unroll
            for (int nt = 0; nt < NT; ++nt) {
                short8 bf = *(const short8*)&Bs[cur][s][nt * 16 + l16][q * 8];
#pragma unroll
                for (int f = 0; f < 4; ++f)
                    acc[f][nt] = __builtin_amdgcn_mfma_f32_16x16x32_bf16(af[f], bf, acc[f][nt], 0, 0, 0);
            }
        }
        if (chunk + 1 < NCHUNK) {
#pragma unroll
            for (int i = 0; i < NSTG; ++i) {
                int v = tid + i * NW * 64;
                int s = v / (COT * 4);
                int rem = v - s * (COT * 4);
                *(short8*)((short*)&Bs[cur ^ 1][s][0][0] + rem * 8) = nb[i];
            }
            __syncthreads();
        }
    }
#pragma unroll
    for (int f = 0; f < 4; ++f)
#pragma unroll
        for (int nt = 0; nt < NT; ++nt)
#pragma unroll
            for (int rg = 0; rg < 4; ++rg) {
                int mg = bm * (NW * 64) + wave * 64 + f * 16 + q * 4 + rg;
                int co = bco * COT + nt * 16 + l16;
                outX[(size_t)mg * COUT + co] = acc[f][nt][rg];
            }
#pragma unroll
    for (int nt = 0; nt < NT; ++nt) {
        float s = 0.f, s2 = 0.f;
#pragma unroll
        for (int f = 0; f < 4; ++f)
#pragma unroll
            for (int rg = 0; rg < 4; ++rg) {
                float v = acc[f][nt][rg];
                s += v; s2 = fmaf(v, v, s2);
            }
        s += __shfl_xor(s, 16); s += __shfl_xor(s, 32);
        s2 += __shfl_xor(s2, 16); s2 += __shfl_xor(s2, 32);
        if (q == 0) {
            sred[wave][0][nt * 16 + l16] = s;
            sred[wave][1][nt * 16 + l16] = s2;
        }
    }
    __syncthreads();
    if (tid < COT) {
        float ts = 0.f, ts2 = 0.f;
#pragma unroll
        for (int w = 0; w < NW; ++w) { ts += sred[w][0][tid]; ts2 += sred[w][1][tid]; }
        atomicAdd(&stacc[bco * COT + tid], ts);
        atomicAdd(&stacc[COUT + bco * COT + tid], ts2);
    }
}

// --------------------------------------------------- conv4 split-K GEMM -----
__global__ __launch_bounds__(256) void conv4_mfma(const unsigned short* __restrict__ A,
                                                  const float* __restrict__ w4,
                                                  float* __restrict__ h4) {
    constexpr int CH = 4, NCHUNK = 8;
    __shared__ short Bs[CH][64][40];
    int tid = threadIdx.x;
    int bco = blockIdx.x & 15;
    int ks = blockIdx.x >> 4;
    int wave = tid >> 6, lane = tid & 63, q = lane >> 4, l16 = lane & 15;
    const short* aBase = (const short*)A + (size_t)(wave * 16 + l16) * 16384 + ks * 1024 + q * 8;
    int r = tid >> 2, cc = tid & 3;
    const float* bg = w4 + (size_t)(bco * 64 + r) * 16384 + ks * 1024 + cc * 8;

    floatx4 acc[4];
#pragma unroll
    for (int nt = 0; nt < 4; ++nt) acc[nt] = (floatx4){0.f, 0.f, 0.f, 0.f};

    short8 nb[CH];
#pragma unroll
    for (int s = 0; s < CH; ++s) {
        float4 b0 = *(const float4*)(bg + s * 32);
        float4 b1 = *(const float4*)(bg + s * 32 + 4);
        nb[s][0] = (short)f2bf(b0.x); nb[s][1] = (short)f2bf(b0.y);
        nb[s][2] = (short)f2bf(b0.z); nb[s][3] = (short)f2bf(b0.w);
        nb[s][4] = (short)f2bf(b1.x); nb[s][5] = (short)f2bf(b1.y);
        nb[s][6] = (short)f2bf(b1.z); nb[s][7] = (short)f2bf(b1.w);
    }
#pragma unroll
    for (int s = 0; s < CH; ++s) *(short8*)&Bs[s][r][cc * 8] = nb[s];
    __syncthreads();

    for (int chunk = 0; chunk < NCHUNK; ++chunk) {
        bool has_next = (chunk + 1 < NCHUNK);
        if (has_next) {
#pragma unroll
            for (int s = 0; s < CH; ++s) {
                int step = (chunk + 1) * CH + s;
                float4 b0 = *(const float4*)(bg + step * 32);
                float4 b1 = *(const float4*)(bg + step * 32 + 4);
                nb[s][0] = (short)f2bf(b0.x); nb[s][1] = (short)f2bf(b0.y);
                nb[s][2] = (short)f2bf(b0.z); nb[s][3] = (short)f2bf(b0.w);
                nb[s][4] = (short)f2bf(b1.x); nb[s][5] = (short)f2bf(b1.y);
                nb[s][6] = (short)f2bf(b1.z); nb[s][7] = (short)f2bf(b1.w);
            }
        }
#pragma unroll
        for (int s = 0; s < CH; ++s) {
            int step = chunk * CH + s;
            short8 af = *(const short8*)(aBase + step * 32);
#pragma unroll
            for (int nt = 0; nt < 4; ++nt) {
                short8 bf = *(const short8*)&Bs[s][nt * 16 + l16][q * 8];
                acc[nt] = __builtin_amdgcn_mfma_f32_16x16x32_bf16(af, bf, acc[nt], 0, 0, 0);
            }
        }
        if (has_next) {
            __syncthreads();
#pragma unroll
            for (int s = 0; s < CH; ++s) *(short8*)&Bs[s][r][cc * 8] = nb[s];
            __syncthreads();
        }
    }
#pragma unroll
    for (int nt = 0; nt < 4; ++nt) {
#pragma unroll
        for (int rg = 0; rg < 4; ++rg) {
            int mg = wave * 16 + q * 4 + rg;
            int co = bco * 64 + nt * 16 + l16;
            atomicAdd(&h4[(size_t)mg * 1024 + co], acc[nt][rg]);
        }
    }
}

// ----------------------------------------------------------- batch stats ----
__global__ __launch_bounds__(256) void stats_part(const float* __restrict__ X,
                                                  float* __restrict__ acc,
                                                  int CO, int R, int RPB, int CGLOG) {
    int tid = threadIdx.x;
    int cg = blockIdx.x & ((1 << CGLOG) - 1);
    int rb = blockIdx.x >> CGLOG;
    int c = (cg << 6) + (tid & 63);
    int w = tid >> 6;
    float s = 0.f, s2 = 0.f;
    int rend = min(R, (rb + 1) * RPB);
    for (int r = rb * RPB + w; r < rend; r += 4) {
        float v = X[(size_t)r * CO + c];
        s += v; s2 += v * v;
    }
    __shared__ float ls[4][64], ls2[4][64];
    ls[w][tid & 63] = s; ls2[w][tid & 63] = s2;
    __syncthreads();
    if (tid < 64) {
        float ts = ls[0][tid] + ls[1][tid] + ls[2][tid] + ls[3][tid];
        float ts2 = ls2[0][tid] + ls2[1][tid] + ls2[2][tid] + ls2[3][tid];
        int cc = (cg << 6) + tid;
        atomicAdd(&acc[cc], ts);
        atomicAdd(&acc[CO + cc], ts2);
    }
}

// ---- BN(inline finalize) + lrelu + bf16 -> parity-plane layout, 8-wide -----
__global__ __launch_bounds__(256) void bnpad_plane8(const float* __restrict__ X,
                                                    const float* __restrict__ stacc,
                                                    const float* __restrict__ g,
                                                    const float* __restrict__ bb,
                                                    unsigned short* __restrict__ out,
                                                    int CO_LOG, int OH, int PH,
                                                    int OCTLOG, float invN, int vtotal) {
    int nb8 = gridDim.x >> 3;
    int sb = (blockIdx.x & 7) * nb8 + (blockIdx.x >> 3);
    int vidx = sb * 256 + threadIdx.x;
    if (vidx >= vtotal) return;
    int CO = 1 << CO_LOG;
    int c8 = (vidx & 3) << 3;
    int t = vidx >> 2;
    int xp = t % PH; t /= PH;
    int yp = t % PH; t /= PH;
    int oct = t & ((1 << OCTLOG) - 1); t >>= OCTLOG;
    int px = t & 1, py = (t >> 1) & 1;
    int b = t >> 2;
    int cbase = (oct << 5) + c8;
    int y = 2 * yp + py - 2, x = 2 * xp + px - 2;
    short8 v;
    if ((unsigned)y < (unsigned)OH && (unsigned)x < (unsigned)OH) {
        const float* p = X + (((size_t)(b * OH + y) * OH + x)) * CO + cbase;
        float4 lo = *(const float4*)p;
        float4 hi = *(const float4*)(p + 4);
        float lv[8] = {lo.x, lo.y, lo.z, lo.w, hi.x, hi.y, hi.z, hi.w};
#pragma unroll
        for (int j = 0; j < 8; ++j) {
            int c = cbase + j;
            float mean = stacc[c] * invN;
            float var = fmaxf(stacc[CO + c] * invN - mean * mean, 0.f);
            float sc = g[c] * rsqrtf(var + EPS);
            float sh = bb[c] - mean * sc;
            float f = lv[j] * sc + sh;
            f = f >= 0.f ? f : NEG * f;
            v[j] = (short)f2bf(f);
        }
    } else {
#pragma unroll
        for (int j = 0; j < 8; ++j) v[j] = 0;
    }
    *(short8*)(out + (size_t)vidx * 8) = v;
}

// -- BN(inline finalize) + lrelu + bf16, NHWC -> NCHW, 8-wide (conv4 input) --
__global__ __launch_bounds__(256) void bn_nchw8(const float* __restrict__ X,
                                                const float* __restrict__ stacc,
                                                const float* __restrict__ g,
                                                const float* __restrict__ bb,
                                                unsigned short* __restrict__ out,
                                                int vtotal) {
    int nb8 = gridDim.x >> 3;
    int sb = (blockIdx.x & 7) * nb8 + (blockIdx.x >> 3);
    int vidx = sb * 256 + threadIdx.x;
    if (vidx >= vtotal) return;
    int hw8 = (vidx & 7) << 3;
    int ci = (vidx >> 3) & 255;
    int b = vidx >> 11;
    float mean = stacc[ci] * (1.f / 4096.f);
    float var = fmaxf(stacc[256 + ci] * (1.f / 4096.f) - mean * mean, 0.f);
    float sc = g[ci] * rsqrtf(var + EPS);
    float sh = bb[ci] - mean * sc;
    short8 v;
#pragma unroll
    for (int j = 0; j < 8; ++j) {
        float f = X[((size_t)(b * 64 + hw8 + j)) * 256 + ci] * sc + sh;
        f = f >= 0.f ? f : NEG * f;
        v[j] = (short)f2bf(f);
    }
    *(short8*)(out + (size_t)vidx * 8) = v;
}

// -------------------------------------- conv5 (inline BN4 finalize) ---------
__global__ __launch_bounds__(256) void conv5_kernel(const float* __restrict__ X,
                                                    const float* __restrict__ stacc,
                                                    const float* __restrict__ g,
                                                    const float* __restrict__ bb,
                                                    const float* __restrict__ w5,
                                                    const float* __restrict__ b5,
                                                    float* __restrict__ out) {
    int b = blockIdx.x, tid = threadIdx.x;
    float s = 0.f;
    for (int c = tid; c < 1024; c += 256) {
        float mean = stacc[c] * (1.f / 64.f);
        float var = fmaxf(stacc[1024 + c] * (1.f / 64.f) - mean * mean, 0.f);
        float sc = g[c] * rsqrtf(var + EPS);
        float sh = bb[c] - mean * sc;
        float f = X[(size_t)b * 1024 + c] * sc + sh;
        f = f >= 0.f ? f : NEG * f;
        s = fmaf(f, w5[c], s);
    }
#pragma unroll
    for (int off = 32; off > 0; off >>= 1) s += __shfl_down(s, off);
    __shared__ float ls[4];
    if ((tid & 63) == 0) ls[tid >> 6] = s;
    __syncthreads();
    if (tid == 0) out[b] = ls[0] + ls[1] + ls[2] + ls[3] + b5[0];
}

// ----------------------------------------------------------------- launch ---
extern "C" void kernel_launch(void* const* d_in, const int* in_sizes, int n_in,
                              void* d_out, int out_size, void* d_ws, size_t ws_size,
                              hipStream_t stream) {
    (void)in_sizes; (void)n_in; (void)out_size; (void)ws_size;
    const float* input_data = (const float*)d_in[0];
    const float* w1 = (const float*)d_in[2];
    const float* g1 = (const float*)d_in[3];
    const float* b1 = (const float*)d_in[4];
    const float* w2 = (const float*)d_in[5];
    const float* g2 = (const float*)d_in[6];
    const float* b2 = (const float*)d_in[7];
    const float* w3 = (const float*)d_in[8];
    const float* g3 = (const float*)d_in[9];
    const float* b3 = (const float*)d_in[10];
    const float* w4 = (const float*)d_in[11];
    const float* g4 = (const float*)d_in[12];
    const float* b4 = (const float*)d_in[13];
    const float* w5 = (const float*)d_in[14];
    const float* b5 = (const float*)d_in[15];

    char* ws = (char*)d_ws;
    float* regA = (float*)ws;               // 16.8 MB: conv1out / conv3out
    char* wsB = ws + 16777216;              // 10.7 MB: plane1 / plane2
    char* wsC = wsB + 10616832;             // 9.5 MB: rendered / conv2out / a4
    char* wsD = wsC + 9469952;
    float* h4  = (float*)wsD;                               // 262,144 B
    float* st1 = (float*)(wsD + 262144);                    // 512 B  (64*2)
    float* st2 = (float*)(wsD + 262656);                    // 1024 B (128*2)
    float* st3 = (float*)(wsD + 263680);                    // 2048 B (256*2)
    float* st4 = (float*)(wsD + 265728);                    // 8192 B (1024*2)
    unsigned short* wT1 = (unsigned short*)(wsD + 274432);  // 61,440 B
    unsigned short* wT2 = (unsigned short*)(wsD + 335872);  // 409,600 B
    unsigned short* wT3 = (unsigned short*)(wsD + 745472);  // 1,638,400 B

    unsigned short* rendered = (unsigned short*)wsC;
    float* conv1out = regA;
    unsigned short* plane1 = (unsigned short*)wsB;  // [64][2][2][2][18][18][32] = 10,616,832 B
    float* conv2out = (float*)wsC;
    unsigned short* plane2 = (unsigned short*)wsB;  // [64][2][2][4][10][10][32] = 6,553,600 B
    float* conv3out = regA;
    unsigned short* a4 = (unsigned short*)wsC;

    // fused render + weight transform + zeroing of stats/h4 region (273,920 B)
    head_kernel<<<5211, 256, 0, stream>>>(input_data, rendered, w1, w2, w3,
                                          wT1, wT2, wT3, (float*)wsD);

    // conv1: [65536,480]x[480,64] — 256 blocks x 4 waves, NT=4, CH=5 (coalesced A)
    conv_mfma<16, 64, 68, 10, 5, 3, 1, 4, 5, 4><<<256, 256, 0, stream>>>(rendered, wT1, conv1out, st1);
    // BN1 + lrelu -> parity planes for conv2 (PH=18, OCT=2): 663,552 vec8 elems
    bnpad_plane8<<<2592, 256, 0, stream>>>(conv1out, st1, g1, b1, plane1, 6, 32, 18, 1, 1.f / 65536.f, 663552);

    // conv2: [16384,1600]x[1600,128] — 64m x 4co = 256 blocks x 4 waves, NT=2, CH=10
    conv_plane<128, 18, 8, 4, 10, 4, 2, 10, 4, 1><<<256, 256, 0, stream>>>(plane1, wT2, conv2out, st2);
    // BN2 + lrelu -> parity planes for conv3 (PH=10, OCT=4): 409,600 vec8 elems
    bnpad_plane8<<<1600, 256, 0, stream>>>(conv2out, st2, g2, b2, plane2, 7, 16, 10, 2, 1.f / 16384.f, 409600);

    // conv3: [4096,3200]x[3200,256] — 32m x 8co = 256 blocks x 2 waves, NT=2, CH=10
    conv_plane<256, 10, 6, 3, 20, 8, 2, 10, 2, 2><<<256, 128, 0, stream>>>(plane2, wT3, conv3out, st3);
    bn_nchw8<<<512, 256, 0, stream>>>(conv3out, st3, g3, b3, a4, 131072);

    // conv4: [64,16384] x [1024,16384]^T -> [64,1024], split-K=16
    conv4_mfma<<<256, 256, 0, stream>>>(a4, w4, h4);
    stats_part<<<16, 256, 0, stream>>>(h4, st4, 1024, 64, 64, 4);

    // conv5 (inline BN4)
    conv5_kernel<<<64, 256, 0, stream>>>(h4, st4, g4, b4, w5, b5, (float*)d_out);
}